// Round 1
// baseline (1168.429 us; speedup 1.0000x reference)
//
#include <hip/hip_runtime.h>
#include <hip/hip_bf16.h>

typedef short short8 __attribute__((ext_vector_type(8)));
typedef float f32x4 __attribute__((ext_vector_type(4)));

#define DIM 2048
#define NH 16
#define KV_RANK 512
#define Q_RANK 1536
#define ROPE_D 64
#define NOPE 128
#define VD 128
#define TT 2048
#define QKH 192                  // NOPE + ROPE
#define QD (NH * QKH)            // 3072
#define KVD (KV_RANK + ROPE_D)   // 576
#define KVUP_D (NH * (NOPE + VD)) // 4096

__device__ inline unsigned short f2bf(float f) {
  __hip_bfloat16 h = __float2bfloat16(f);
  union { __hip_bfloat16 h; unsigned short u; } cv; cv.h = h; return cv.u;
}

// ---------------- fp32 -> bf16 convert (vectorized x4) ----------------
__global__ __launch_bounds__(256) void convert_kernel(const float* __restrict__ in,
                                                      unsigned short* __restrict__ out,
                                                      int n4) {
  int i = blockIdx.x * 256 + threadIdx.x;
  if (i >= n4) return;
  float4 v = reinterpret_cast<const float4*>(in)[i];
  ushort4 o;
  o.x = f2bf(v.x); o.y = f2bf(v.y); o.z = f2bf(v.z); o.w = f2bf(v.w);
  reinterpret_cast<ushort4*>(out)[i] = o;
}

// ---------------- generic bf16 GEMM: C[M,N] = A[M,K] * W[N,K]^T -------
// grid = (N/64, M/64), block = 256 (4 waves). Each wave: 32x32 via 2x2 MFMA frags.
__global__ __launch_bounds__(256) void gemm_bf16_nt(const unsigned short* __restrict__ A,
                                                    const unsigned short* __restrict__ W,
                                                    float* __restrict__ C,
                                                    int K, int lda, int ldb, int ldc) {
  __shared__ __align__(16) unsigned short As[64 * 32];
  __shared__ __align__(16) unsigned short Ws[64 * 32];
  const int tid = threadIdx.x;
  const int bm = blockIdx.y * 64, bn = blockIdx.x * 64;
  const int lane = tid & 63, wave = tid >> 6;
  const int wm = (wave >> 1) * 32, wn = (wave & 1) * 32;
  const int srow = tid >> 2, scb = tid & 3;   // staging: row 0..63, 16B col-block 0..3
  const int fr = lane & 15, fkb = lane >> 4;  // fragment row, k-block

  f32x4 acc[2][2] = {};

  const unsigned short* Ap = A + (size_t)(bm + srow) * lda + scb * 8;
  const unsigned short* Wp = W + (size_t)(bn + srow) * ldb + scb * 8;
  const int st = srow * 32 + ((scb ^ (srow & 3)) * 8);  // XOR-swizzled store offset

  for (int k0 = 0; k0 < K; k0 += 32) {
    uint4 av = *reinterpret_cast<const uint4*>(Ap); Ap += 32;
    uint4 wv = *reinterpret_cast<const uint4*>(Wp); Wp += 32;
    *reinterpret_cast<uint4*>(&As[st]) = av;
    *reinterpret_cast<uint4*>(&Ws[st]) = wv;
    __syncthreads();
    short8 a[2], b[2];
#pragma unroll
    for (int i = 0; i < 2; ++i) {
      int ra = wm + i * 16 + fr;
      a[i] = *reinterpret_cast<const short8*>(&As[ra * 32 + ((fkb ^ (ra & 3)) * 8)]);
      int rb = wn + i * 16 + fr;
      b[i] = *reinterpret_cast<const short8*>(&Ws[rb * 32 + ((fkb ^ (rb & 3)) * 8)]);
    }
    acc[0][0] = __builtin_amdgcn_mfma_f32_16x16x32_bf16(a[0], b[0], acc[0][0], 0, 0, 0);
    acc[0][1] = __builtin_amdgcn_mfma_f32_16x16x32_bf16(a[0], b[1], acc[0][1], 0, 0, 0);
    acc[1][0] = __builtin_amdgcn_mfma_f32_16x16x32_bf16(a[1], b[0], acc[1][0], 0, 0, 0);
    acc[1][1] = __builtin_amdgcn_mfma_f32_16x16x32_bf16(a[1], b[1], acc[1][1], 0, 0, 0);
    __syncthreads();
  }
#pragma unroll
  for (int i = 0; i < 2; ++i)
#pragma unroll
    for (int j = 0; j < 2; ++j) {
      int row0 = bm + wm + i * 16 + (lane >> 4) * 4;
      int col = bn + wn + j * 16 + (lane & 15);
#pragma unroll
      for (int r = 0; r < 4; ++r)
        C[(size_t)(row0 + r) * ldc + col] = acc[i][j][r];
    }
}

// ---------------- RMSNorm rows: fp32 in -> bf16 out -------------------
__global__ __launch_bounds__(256) void rmsnorm_kernel(const float* __restrict__ in,
                                                      const float* __restrict__ w,
                                                      unsigned short* __restrict__ out,
                                                      int cols, int in_stride, int out_stride) {
  const int row = blockIdx.x, tid = threadIdx.x;
  const float* x = in + (size_t)row * in_stride;
  float ss = 0.f;
  for (int c = tid; c < cols; c += 256) { float v = x[c]; ss += v * v; }
  __shared__ float red[256];
  red[tid] = ss; __syncthreads();
  for (int off = 128; off > 0; off >>= 1) {
    if (tid < off) red[tid] += red[tid + off];
    __syncthreads();
  }
  float r = rsqrtf(red[0] / (float)cols + 1e-6f);
  for (int c = tid; c < cols; c += 256)
    out[(size_t)row * out_stride + c] = f2bf(x[c] * r * w[c]);
}

// ---------------- RoPE: in-place on q, k_rope extraction --------------
__global__ __launch_bounds__(256) void rope_kernel(float* __restrict__ q,
                                                   const float* __restrict__ kv,
                                                   float* __restrict__ krope) {
  const int t = blockIdx.x, tid = threadIdx.x;
  for (int p = tid; p < NH * 32 + 32; p += 256) {
    int j = (p < NH * 32) ? (p & 31) : (p - NH * 32);
    float inv = powf(500000.0f, -(float)(2 * j) * (1.0f / 64.0f));
    float ang = (float)t * inv;
    float sv, cv;
    sincosf(ang, &sv, &cv);
    if (p < NH * 32) {
      int h = p >> 5;
      float* b = q + (size_t)t * QD + h * QKH + NOPE + 2 * j;
      float e = b[0], o = b[1];
      b[0] = e * cv - o * sv;
      b[1] = o * cv + e * sv;
    } else {
      const float* b = kv + (size_t)t * KVD + KV_RANK + 2 * j;
      float e = b[0], o = b[1];
      krope[(size_t)t * ROPE_D + 2 * j]     = e * cv - o * sv;
      krope[(size_t)t * ROPE_D + 2 * j + 1] = o * cv + e * sv;
    }
  }
}

// ---------------- attention helpers ----------------
__device__ inline float4 f4max(float4 a, float4 b) {
  return make_float4(fmaxf(a.x, b.x), fmaxf(a.y, b.y), fmaxf(a.z, b.z), fmaxf(a.w, b.w));
}
__device__ inline float4 f4add(float4 a, float4 b) {
  return make_float4(a.x + b.x, a.y + b.y, a.z + b.z, a.w + b.w);
}
__device__ inline float4 f4sub(float4 a, float4 b) {
  return make_float4(a.x - b.x, a.y - b.y, a.z - b.z, a.w - b.w);
}
__device__ inline float4 f4mul(float4 a, float4 b) {
  return make_float4(a.x * b.x, a.y * b.y, a.z * b.z, a.w * b.w);
}
__device__ inline float4 f4exp(float4 a) {
  return make_float4(expf(a.x), expf(a.y), expf(a.z), expf(a.w));
}
__device__ inline void f4fma(float4& d, float s, float4 v) {
  d.x += s * v.x; d.y += s * v.y; d.z += s * v.z; d.w += s * v.w;
}
__device__ inline void f4scale(float4& d, float s) {
  d.x *= s; d.y *= s; d.z *= s; d.w *= s;
}

// ---------------- causal flash attention, 4 q-rows per block ----------
// grid = (T/4, H), block = 256. out[t, h*128+d].
__global__ __launch_bounds__(256) void attn_kernel(const float* __restrict__ q,
                                                   const float* __restrict__ kvup,
                                                   const float* __restrict__ krope,
                                                   float* __restrict__ out) {
  const int h = blockIdx.y;
  const int t0 = blockIdx.x * 4;
  const int tid = threadIdx.x;
  const int g = tid & 31, sl = tid >> 5;  // dim-group (4 dims), k-slice (32 ks)
  __shared__ __align__(16) float qs[4 * QKH];
  __shared__ __align__(16) float4 ps4[256];
  __shared__ __align__(16) float4 red4[256];

  for (int i = tid; i < 4 * QKH; i += 256) {
    int r = i / QKH, c = i - r * QKH;
    qs[i] = q[(size_t)(t0 + r) * QD + h * QKH + c];
  }
  __syncthreads();

  float4 m = make_float4(-1e30f, -1e30f, -1e30f, -1e30f);
  float4 lsum = make_float4(0.f, 0.f, 0.f, 0.f);
  float4 acc0 = make_float4(0.f, 0.f, 0.f, 0.f);
  float4 acc1 = acc0, acc2 = acc0, acc3 = acc0;
  const float scale = 0.0721687836487032f;  // 1/sqrt(192)
  const int tmax = t0 + 3;
  const float4* qb = reinterpret_cast<const float4*>(qs);

  for (int kc = 0; kc <= tmax; kc += 256) {
    const int k = kc + tid;
    float sa0 = 0.f, sa1 = 0.f, sa2 = 0.f, sa3 = 0.f;
    if (k <= tmax) {
      const float4* kr = reinterpret_cast<const float4*>(kvup + (size_t)k * KVUP_D + h * 256);
#pragma unroll 8
      for (int j = 0; j < 32; ++j) {
        float4 v = kr[j];
        float4 q0 = qb[j], q1 = qb[48 + j], q2 = qb[96 + j], q3 = qb[144 + j];
        sa0 += q0.x * v.x + q0.y * v.y + q0.z * v.z + q0.w * v.w;
        sa1 += q1.x * v.x + q1.y * v.y + q1.z * v.z + q1.w * v.w;
        sa2 += q2.x * v.x + q2.y * v.y + q2.z * v.z + q2.w * v.w;
        sa3 += q3.x * v.x + q3.y * v.y + q3.z * v.z + q3.w * v.w;
      }
      const float4* ko = reinterpret_cast<const float4*>(krope + (size_t)k * ROPE_D);
#pragma unroll 4
      for (int j = 0; j < 16; ++j) {
        float4 v = ko[j];
        float4 q0 = qb[32 + j], q1 = qb[80 + j], q2 = qb[128 + j], q3 = qb[176 + j];
        sa0 += q0.x * v.x + q0.y * v.y + q0.z * v.z + q0.w * v.w;
        sa1 += q1.x * v.x + q1.y * v.y + q1.z * v.z + q1.w * v.w;
        sa2 += q2.x * v.x + q2.y * v.y + q2.z * v.z + q2.w * v.w;
        sa3 += q3.x * v.x + q3.y * v.y + q3.z * v.z + q3.w * v.w;
      }
    }
    float4 sv;
    sv.x = (k <= t0)     ? sa0 * scale : -1e30f;
    sv.y = (k <= t0 + 1) ? sa1 * scale : -1e30f;
    sv.z = (k <= t0 + 2) ? sa2 * scale : -1e30f;
    sv.w = (k <= tmax)   ? sa3 * scale : -1e30f;

    red4[tid] = sv; __syncthreads();
#pragma unroll
    for (int off = 128; off > 0; off >>= 1) {
      if (tid < off) red4[tid] = f4max(red4[tid], red4[tid + off]);
      __syncthreads();
    }
    float4 cmax = red4[0];
    __syncthreads();
    float4 mnew = f4max(m, cmax);
    float4 corr = f4exp(f4sub(m, mnew));
    float4 p = f4exp(f4sub(sv, mnew));
    ps4[tid] = p;
    red4[tid] = p; __syncthreads();
#pragma unroll
    for (int off = 128; off > 0; off >>= 1) {
      if (tid < off) red4[tid] = f4add(red4[tid], red4[tid + off]);
      __syncthreads();
    }
    float4 csum = red4[0];
    lsum = f4add(f4mul(lsum, corr), csum);
    m = mnew;
    f4scale(acc0, corr.x); f4scale(acc1, corr.y); f4scale(acc2, corr.z); f4scale(acc3, corr.w);

    // PV: slice sl handles ks [kc+sl*32, kc+sl*32+32); rotate kk by sl to dodge LDS bank aliasing
    const float* vbase = kvup + (size_t)(kc + sl * 32) * KVUP_D + h * 256 + NOPE + g * 4;
#pragma unroll 4
    for (int kk = 0; kk < 32; ++kk) {
      int kk2 = (kk + sl) & 31;
      float4 pv = ps4[sl * 32 + kk2];
      float4 v = *reinterpret_cast<const float4*>(vbase + (size_t)kk2 * KVUP_D);
      f4fma(acc0, pv.x, v); f4fma(acc1, pv.y, v); f4fma(acc2, pv.z, v); f4fma(acc3, pv.w, v);
    }
    __syncthreads();
  }

#pragma unroll
  for (int r = 0; r < 4; ++r) {
    float4 a = (r == 0) ? acc0 : (r == 1) ? acc1 : (r == 2) ? acc2 : acc3;
    red4[tid] = a; __syncthreads();
    if (tid < 128) red4[tid] = f4add(red4[tid], red4[tid + 128]);
    __syncthreads();
    if (tid < 64) red4[tid] = f4add(red4[tid], red4[tid + 64]);
    __syncthreads();
    if (tid < 32) {
      float4 t = f4add(red4[tid], red4[tid + 32]);
      float lr = (r == 0) ? lsum.x : (r == 1) ? lsum.y : (r == 2) ? lsum.z : lsum.w;
      float linv = 1.0f / lr;
      float4 o = make_float4(t.x * linv, t.y * linv, t.z * linv, t.w * linv);
      *reinterpret_cast<float4*>(out + (size_t)(t0 + r) * (NH * VD) + h * VD + tid * 4) = o;
    }
    __syncthreads();
  }
}

// ---------------- launch ----------------
extern "C" void kernel_launch(void* const* d_in, const int* in_sizes, int n_in,
                              void* d_out, int out_size, void* d_ws, size_t ws_size,
                              hipStream_t stream) {
  const float* x        = (const float*)d_in[0];
  const float* w_q_down = (const float*)d_in[1];
  const float* q_norm_w = (const float*)d_in[2];
  const float* w_q_up   = (const float*)d_in[3];
  const float* w_kv_down= (const float*)d_in[4];
  const float* kv_norm_w= (const float*)d_in[5];
  const float* w_kv_up  = (const float*)d_in[6];
  const float* w_o      = (const float*)d_in[7];
  float* outp = (float*)d_out;

  char* ws = (char*)d_ws;
  size_t off = 0;
  auto alloc = [&](size_t bytes) {
    void* p = ws + off;
    off += (bytes + 255) & ~(size_t)255;
    return p;
  };
  float* cq_raw = (float*)alloc((size_t)TT * Q_RANK * 4);
  float* kv     = (float*)alloc((size_t)TT * KVD * 4);
  float* qbuf   = (float*)alloc((size_t)TT * QD * 4);
  float* kvup   = (float*)alloc((size_t)TT * KVUP_D * 4);
  float* krope  = (float*)alloc((size_t)TT * ROPE_D * 4);
  float* attn   = (float*)alloc((size_t)TT * DIM * 4);
  unsigned short* x_bf    = (unsigned short*)alloc((size_t)TT * DIM * 2);
  unsigned short* wqd_bf  = (unsigned short*)alloc((size_t)Q_RANK * DIM * 2);
  unsigned short* wqu_bf  = (unsigned short*)alloc((size_t)QD * Q_RANK * 2);
  unsigned short* wkvd_bf = (unsigned short*)alloc((size_t)KVD * DIM * 2);
  unsigned short* wkvu_bf = (unsigned short*)alloc((size_t)KVUP_D * KV_RANK * 2);
  unsigned short* wo_bf   = (unsigned short*)alloc((size_t)DIM * DIM * 2);
  unsigned short* cq_bf   = (unsigned short*)alloc((size_t)TT * Q_RANK * 2);
  unsigned short* ckv_bf  = (unsigned short*)alloc((size_t)TT * KV_RANK * 2);
  unsigned short* attn_bf = (unsigned short*)alloc((size_t)TT * DIM * 2);

  auto conv = [&](const float* in, unsigned short* out, size_t n) {
    int n4 = (int)(n / 4);
    convert_kernel<<<dim3((n4 + 255) / 256), dim3(256), 0, stream>>>(in, out, n4);
  };
  conv(x, x_bf, (size_t)TT * DIM);
  conv(w_q_down, wqd_bf, (size_t)Q_RANK * DIM);
  conv(w_q_up, wqu_bf, (size_t)QD * Q_RANK);
  conv(w_kv_down, wkvd_bf, (size_t)KVD * DIM);
  conv(w_kv_up, wkvu_bf, (size_t)KVUP_D * KV_RANK);
  conv(w_o, wo_bf, (size_t)DIM * DIM);

  dim3 blk(256);
  // cq_raw = x @ w_q_down^T   [2048 x 1536]
  gemm_bf16_nt<<<dim3(Q_RANK / 64, TT / 64), blk, 0, stream>>>(x_bf, wqd_bf, cq_raw, DIM, DIM, DIM, Q_RANK);
  // kv = x @ w_kv_down^T      [2048 x 576]
  gemm_bf16_nt<<<dim3(KVD / 64, TT / 64), blk, 0, stream>>>(x_bf, wkvd_bf, kv, DIM, DIM, DIM, KVD);
  // rmsnorm
  rmsnorm_kernel<<<dim3(TT), blk, 0, stream>>>(cq_raw, q_norm_w, cq_bf, Q_RANK, Q_RANK, Q_RANK);
  rmsnorm_kernel<<<dim3(TT), blk, 0, stream>>>(kv, kv_norm_w, ckv_bf, KV_RANK, KVD, KV_RANK);
  // q = c_q @ w_q_up^T        [2048 x 3072]
  gemm_bf16_nt<<<dim3(QD / 64, TT / 64), blk, 0, stream>>>(cq_bf, wqu_bf, qbuf, Q_RANK, Q_RANK, Q_RANK, QD);
  // kv_up = c_kv @ w_kv_up^T  [2048 x 4096]
  gemm_bf16_nt<<<dim3(KVUP_D / 64, TT / 64), blk, 0, stream>>>(ckv_bf, wkvu_bf, kvup, KV_RANK, KV_RANK, KV_RANK, KVUP_D);
  // rope (q in-place, krope out)
  rope_kernel<<<dim3(TT), blk, 0, stream>>>(qbuf, kv, krope);
  // attention
  attn_kernel<<<dim3(TT / 4, NH), blk, 0, stream>>>(qbuf, kvup, krope, attn);
  // attn -> bf16, final GEMM
  conv(attn, attn_bf, (size_t)TT * DIM);
  gemm_bf16_nt<<<dim3(DIM / 64, TT / 64), blk, 0, stream>>>(attn_bf, wo_bf, outp, DIM, DIM, DIM, DIM);
}

// Round 2
// 353.796 us; speedup vs baseline: 3.3026x; 3.3026x over previous
//
#include <hip/hip_runtime.h>
#include <hip/hip_bf16.h>

typedef short short8 __attribute__((ext_vector_type(8)));
typedef float f32x4 __attribute__((ext_vector_type(4)));

#define DIM 2048
#define NH 16
#define KV_RANK 512
#define Q_RANK 1536
#define ROPE_D 64
#define NOPE 128
#define VD 128
#define TT 2048
#define QKH 192                   // NOPE + ROPE
#define QD (NH * QKH)             // 3072
#define KVD (KV_RANK + ROPE_D)    // 576
#define KVUP_D (NH * (NOPE + VD)) // 4096

__device__ inline unsigned short f2bf(float f) {
  __hip_bfloat16 h = __float2bfloat16(f);
  union { __hip_bfloat16 h; unsigned short u; } cv; cv.h = h; return cv.u;
}

// ---------------- fp32 -> bf16 convert (vectorized x4) ----------------
__global__ __launch_bounds__(256) void convert_kernel(const float* __restrict__ in,
                                                      unsigned short* __restrict__ out,
                                                      int n4) {
  int i = blockIdx.x * 256 + threadIdx.x;
  if (i >= n4) return;
  float4 v = reinterpret_cast<const float4*>(in)[i];
  ushort4 o;
  o.x = f2bf(v.x); o.y = f2bf(v.y); o.z = f2bf(v.z); o.w = f2bf(v.w);
  reinterpret_cast<ushort4*>(out)[i] = o;
}

// ---------------- generic bf16 GEMM: C[M,N] = A[M,K] * W[N,K]^T -------
__global__ __launch_bounds__(256) void gemm_bf16_nt(const unsigned short* __restrict__ A,
                                                    const unsigned short* __restrict__ W,
                                                    float* __restrict__ C,
                                                    int K, int lda, int ldb, int ldc) {
  __shared__ __align__(16) unsigned short As[64 * 32];
  __shared__ __align__(16) unsigned short Ws[64 * 32];
  const int tid = threadIdx.x;
  const int bm = blockIdx.y * 64, bn = blockIdx.x * 64;
  const int lane = tid & 63, wave = tid >> 6;
  const int wm = (wave >> 1) * 32, wn = (wave & 1) * 32;
  const int srow = tid >> 2, scb = tid & 3;
  const int fr = lane & 15, fkb = lane >> 4;

  f32x4 acc[2][2] = {};

  const unsigned short* Ap = A + (size_t)(bm + srow) * lda + scb * 8;
  const unsigned short* Wp = W + (size_t)(bn + srow) * ldb + scb * 8;
  const int st = srow * 32 + ((scb ^ (srow & 3)) * 8);

  for (int k0 = 0; k0 < K; k0 += 32) {
    uint4 av = *reinterpret_cast<const uint4*>(Ap); Ap += 32;
    uint4 wv = *reinterpret_cast<const uint4*>(Wp); Wp += 32;
    *reinterpret_cast<uint4*>(&As[st]) = av;
    *reinterpret_cast<uint4*>(&Ws[st]) = wv;
    __syncthreads();
    short8 a[2], b[2];
#pragma unroll
    for (int i = 0; i < 2; ++i) {
      int ra = wm + i * 16 + fr;
      a[i] = *reinterpret_cast<const short8*>(&As[ra * 32 + ((fkb ^ (ra & 3)) * 8)]);
      int rb = wn + i * 16 + fr;
      b[i] = *reinterpret_cast<const short8*>(&Ws[rb * 32 + ((fkb ^ (rb & 3)) * 8)]);
    }
    acc[0][0] = __builtin_amdgcn_mfma_f32_16x16x32_bf16(a[0], b[0], acc[0][0], 0, 0, 0);
    acc[0][1] = __builtin_amdgcn_mfma_f32_16x16x32_bf16(a[0], b[1], acc[0][1], 0, 0, 0);
    acc[1][0] = __builtin_amdgcn_mfma_f32_16x16x32_bf16(a[1], b[0], acc[1][0], 0, 0, 0);
    acc[1][1] = __builtin_amdgcn_mfma_f32_16x16x32_bf16(a[1], b[1], acc[1][1], 0, 0, 0);
    __syncthreads();
  }
#pragma unroll
  for (int i = 0; i < 2; ++i)
#pragma unroll
    for (int j = 0; j < 2; ++j) {
      int row0 = bm + wm + i * 16 + (lane >> 4) * 4;
      int col = bn + wn + j * 16 + (lane & 15);
#pragma unroll
      for (int r = 0; r < 4; ++r)
        C[(size_t)(row0 + r) * ldc + col] = acc[i][j][r];
    }
}

// ---------------- RMSNorm rows: fp32 in -> bf16 out -------------------
__global__ __launch_bounds__(256) void rmsnorm_kernel(const float* __restrict__ in,
                                                      const float* __restrict__ w,
                                                      unsigned short* __restrict__ out,
                                                      int cols, int in_stride, int out_stride) {
  const int row = blockIdx.x, tid = threadIdx.x;
  const float* x = in + (size_t)row * in_stride;
  float ss = 0.f;
  for (int c = tid; c < cols; c += 256) { float v = x[c]; ss += v * v; }
  __shared__ float red[256];
  red[tid] = ss; __syncthreads();
  for (int off = 128; off > 0; off >>= 1) {
    if (tid < off) red[tid] += red[tid + off];
    __syncthreads();
  }
  float r = rsqrtf(red[0] / (float)cols + 1e-6f);
  for (int c = tid; c < cols; c += 256)
    out[(size_t)row * out_stride + c] = f2bf(x[c] * r * w[c]);
}

// ------- RoPE on q (fp32 -> bf16 full row) + k_rope extraction (bf16) -------
__global__ __launch_bounds__(256) void rope_q_kernel(const float* __restrict__ q,
                                                     const float* __restrict__ kv,
                                                     unsigned short* __restrict__ qb,
                                                     unsigned short* __restrict__ kr) {
  const int t = blockIdx.x, tid = threadIdx.x;
  const float* qrow = q + (size_t)t * QD;
  unsigned short* qorow = qb + (size_t)t * QD;
  for (int i = tid; i < NH * NOPE; i += 256) {
    int h = i >> 7, c = i & 127;
    qorow[h * QKH + c] = f2bf(qrow[h * QKH + c]);
  }
  for (int p = tid; p < NH * 32 + 32; p += 256) {
    int j = (p < NH * 32) ? (p & 31) : (p - NH * 32);
    float inv = powf(500000.0f, -(float)(2 * j) * (1.0f / 64.0f));
    float ang = (float)t * inv;
    float sv, cv;
    sincosf(ang, &sv, &cv);
    if (p < NH * 32) {
      int h = p >> 5;
      const float* b = qrow + h * QKH + NOPE + 2 * j;
      float e = b[0], o = b[1];
      qorow[h * QKH + NOPE + 2 * j]     = f2bf(e * cv - o * sv);
      qorow[h * QKH + NOPE + 2 * j + 1] = f2bf(o * cv + e * sv);
    } else {
      const float* b = kv + (size_t)t * KVD + KV_RANK + 2 * j;
      float e = b[0], o = b[1];
      kr[(size_t)t * ROPE_D + 2 * j]     = f2bf(e * cv - o * sv);
      kr[(size_t)t * ROPE_D + 2 * j + 1] = f2bf(o * cv + e * sv);
    }
  }
}

// ------- V^T: vt[h*128+d][t] = bf16(kvup[t][h*256+128+d]) -------
__global__ __launch_bounds__(256) void vtrans_kernel(const float* __restrict__ kvup,
                                                     unsigned short* __restrict__ vt) {
  __shared__ unsigned short tile[64][65];
  const int h = blockIdx.z;
  const int t0 = blockIdx.x * 64;
  const int d0 = blockIdx.y * 64;
  const int tid = threadIdx.x;
  const int r = tid >> 2, cb = tid & 3;
  const float* src = kvup + (size_t)(t0 + r) * KVUP_D + h * 256 + NOPE + d0 + cb * 16;
#pragma unroll
  for (int e = 0; e < 16; e += 4) {
    float4 v = *reinterpret_cast<const float4*>(src + e);
    tile[r][cb * 16 + e]     = f2bf(v.x);
    tile[r][cb * 16 + e + 1] = f2bf(v.y);
    tile[r][cb * 16 + e + 2] = f2bf(v.z);
    tile[r][cb * 16 + e + 3] = f2bf(v.w);
  }
  __syncthreads();
  unsigned short* dst = vt + (size_t)(h * VD + d0 + r) * TT + t0 + cb * 16;
#pragma unroll
  for (int e = 0; e < 16; e += 4) {
    ushort4 w;
    w.x = tile[cb * 16 + e + 0][r];
    w.y = tile[cb * 16 + e + 1][r];
    w.z = tile[cb * 16 + e + 2][r];
    w.w = tile[cb * 16 + e + 3][r];
    *reinterpret_cast<ushort4*>(dst + e) = w;
  }
}

// ---------------- MFMA flash attention ----------------
// grid = (T/64, H), block = 256 (4 waves). Wave w owns q-rows [t0+16w, t0+16w+16).
#define KS_STRIDE 200  // 192 + 8 pad: row stride 400B -> 2-way banks only
#define VS_STRIDE 72   // 64 + 8
#define PS_STRIDE 72   // 64 + 8
__global__ __launch_bounds__(256) void attn_mfma_kernel(
    const unsigned short* __restrict__ qb,     // [T][3072] bf16 (rope applied)
    const unsigned short* __restrict__ kvupb,  // [T][4096] bf16
    const unsigned short* __restrict__ kropeb, // [T][64] bf16
    const unsigned short* __restrict__ vtb,    // [H*128][T] bf16
    unsigned short* __restrict__ out)          // [T][2048] bf16
{
  const int h = blockIdx.y;
  const int t0 = (gridDim.x - 1 - blockIdx.x) * 64;  // heavy tiles dispatched first
  const int tid = threadIdx.x;
  const int lane = tid & 63, wave = tid >> 6;
  const int fr = lane & 15, fg = lane >> 4;

  __shared__ __align__(16) unsigned short Ks[64 * KS_STRIDE];
  __shared__ __align__(16) unsigned short Vs[128 * VS_STRIDE];
  __shared__ __align__(16) unsigned short Ps[4][16 * PS_STRIDE];

  // Q fragments: row = fr (A-frag row), k = kc*32 + fg*8 + e
  short8 qf[6];
  {
    const unsigned short* qrow = qb + (size_t)(t0 + wave * 16 + fr) * QD + h * QKH;
#pragma unroll
    for (int kc = 0; kc < 6; ++kc)
      qf[kc] = *reinterpret_cast<const short8*>(qrow + kc * 32 + fg * 8);
  }

  f32x4 o[8] = {};
  float m[4] = {-1e30f, -1e30f, -1e30f, -1e30f};
  float l[4] = {0.f, 0.f, 0.f, 0.f};
  const float scale = 0.0721687836487032f;  // 1/sqrt(192)

  const int nkt = t0 / 64 + 1;
  for (int kt = 0; kt < nkt; ++kt) {
    const int kt0 = kt * 64;
    // stage K (64 rows x 192: nope cols 0..127 from kvup, rope cols 128..191)
#pragma unroll
    for (int i = 0; i < 6; ++i) {
      int c = tid + i * 256;
      int row = c / 24, cb = c % 24;
      const unsigned short* src = (cb < 16)
        ? kvupb + (size_t)(kt0 + row) * KVUP_D + h * 256 + cb * 8
        : kropeb + (size_t)(kt0 + row) * ROPE_D + (cb - 16) * 8;
      *reinterpret_cast<uint4*>(&Ks[row * KS_STRIDE + cb * 8]) =
        *reinterpret_cast<const uint4*>(src);
    }
    // stage V^T (128 d-rows x 64 keys)
#pragma unroll
    for (int i = 0; i < 4; ++i) {
      int c = tid + i * 256;
      int d = c / 8, cb = c % 8;
      *reinterpret_cast<uint4*>(&Vs[d * VS_STRIDE + cb * 8]) =
        *reinterpret_cast<const uint4*>(vtb + (size_t)(h * VD + d) * TT + kt0 + cb * 8);
    }
    __syncthreads();

    // S = Q K^T : 16 x 64 per wave (4 tiles of 16x16)
    f32x4 s[4] = {};
#pragma unroll
    for (int kc = 0; kc < 6; ++kc) {
#pragma unroll
      for (int j = 0; j < 4; ++j) {
        short8 b = *reinterpret_cast<const short8*>(
            &Ks[(j * 16 + fr) * KS_STRIDE + kc * 32 + fg * 8]);
        s[j] = __builtin_amdgcn_mfma_f32_16x16x32_bf16(qf[kc], b, s[j], 0, 0, 0);
      }
    }

    const bool diag = (kt0 == t0);
    // online softmax per output row (reg r -> row fg*4+r)
#pragma unroll
    for (int r = 0; r < 4; ++r) {
      float sv[4];
#pragma unroll
      for (int j = 0; j < 4; ++j) {
        float x = s[j][r] * scale;
        if (diag && (j * 16 + fr) > (wave * 16 + fg * 4 + r)) x = -1e30f;
        sv[j] = x;
      }
      float mx = fmaxf(fmaxf(sv[0], sv[1]), fmaxf(sv[2], sv[3]));
#pragma unroll
      for (int off = 1; off < 16; off <<= 1)
        mx = fmaxf(mx, __shfl_xor(mx, off));
      float mn = fmaxf(m[r], mx);
      float corr = __expf(m[r] - mn);
      m[r] = mn;
      float ssum = 0.f;
      float p[4];
#pragma unroll
      for (int j = 0; j < 4; ++j) {
        p[j] = __expf(sv[j] - mn);
        ssum += p[j];
      }
#pragma unroll
      for (int off = 1; off < 16; off <<= 1)
        ssum += __shfl_xor(ssum, off);
      l[r] = l[r] * corr + ssum;
#pragma unroll
      for (int dj = 0; dj < 8; ++dj) o[dj][r] *= corr;
#pragma unroll
      for (int j = 0; j < 4; ++j)
        Ps[wave][(fg * 4 + r) * PS_STRIDE + j * 16 + fr] = f2bf(p[j]);
    }

    // O += P V : P A-frag from Ps (row=fr, k=kc*32+fg*8+e), V^T B-frag from Vs
#pragma unroll
    for (int kc = 0; kc < 2; ++kc) {
      short8 p = *reinterpret_cast<const short8*>(
          &Ps[wave][fr * PS_STRIDE + kc * 32 + fg * 8]);
#pragma unroll
      for (int dj = 0; dj < 8; ++dj) {
        short8 b = *reinterpret_cast<const short8*>(
            &Vs[(dj * 16 + fr) * VS_STRIDE + kc * 32 + fg * 8]);
        o[dj] = __builtin_amdgcn_mfma_f32_16x16x32_bf16(p, b, o[dj], 0, 0, 0);
      }
    }
    __syncthreads();
  }

  // epilogue: write bf16
#pragma unroll
  for (int r = 0; r < 4; ++r) {
    float linv = 1.0f / l[r];
    int trow = t0 + wave * 16 + fg * 4 + r;
    unsigned short* orow = out + (size_t)trow * DIM + h * VD;
#pragma unroll
    for (int dj = 0; dj < 8; ++dj)
      orow[dj * 16 + fr] = f2bf(o[dj][r] * linv);
  }
}

// ---------------- launch ----------------
extern "C" void kernel_launch(void* const* d_in, const int* in_sizes, int n_in,
                              void* d_out, int out_size, void* d_ws, size_t ws_size,
                              hipStream_t stream) {
  const float* x        = (const float*)d_in[0];
  const float* w_q_down = (const float*)d_in[1];
  const float* q_norm_w = (const float*)d_in[2];
  const float* w_q_up   = (const float*)d_in[3];
  const float* w_kv_down= (const float*)d_in[4];
  const float* kv_norm_w= (const float*)d_in[5];
  const float* w_kv_up  = (const float*)d_in[6];
  const float* w_o      = (const float*)d_in[7];
  float* outp = (float*)d_out;

  char* ws = (char*)d_ws;
  size_t off = 0;
  auto alloc = [&](size_t bytes) {
    void* p = ws + off;
    off += (bytes + 255) & ~(size_t)255;
    return p;
  };
  float* cq_raw = (float*)alloc((size_t)TT * Q_RANK * 4);   // also reused for vtb
  float* kv     = (float*)alloc((size_t)TT * KVD * 4);
  float* qbuf   = (float*)alloc((size_t)TT * QD * 4);
  float* kvup   = (float*)alloc((size_t)TT * KVUP_D * 4);
  unsigned short* x_bf    = (unsigned short*)alloc((size_t)TT * DIM * 2);  // also reused for attn_bf
  unsigned short* wqd_bf  = (unsigned short*)alloc((size_t)Q_RANK * DIM * 2);
  unsigned short* wqu_bf  = (unsigned short*)alloc((size_t)QD * Q_RANK * 2);
  unsigned short* wkvd_bf = (unsigned short*)alloc((size_t)KVD * DIM * 2);
  unsigned short* wkvu_bf = (unsigned short*)alloc((size_t)KVUP_D * KV_RANK * 2);
  unsigned short* wo_bf   = (unsigned short*)alloc((size_t)DIM * DIM * 2);
  unsigned short* cq_bf   = (unsigned short*)alloc((size_t)TT * Q_RANK * 2);
  unsigned short* ckv_bf  = (unsigned short*)alloc((size_t)TT * KV_RANK * 2);
  unsigned short* qb_bf   = (unsigned short*)alloc((size_t)TT * QD * 2);
  unsigned short* kvup_bf = (unsigned short*)alloc((size_t)TT * KVUP_D * 2);
  unsigned short* krope_bf= (unsigned short*)alloc((size_t)TT * ROPE_D * 2);
  // aliases (regions dead by the time these are written)
  unsigned short* vtb     = (unsigned short*)cq_raw;  // [H*128][T] bf16 = 8.4MB < 12.6MB
  unsigned short* attn_bf = x_bf;                     // [T][2048] bf16, x_bf dead after down-GEMMs

  auto conv = [&](const float* in, unsigned short* out, size_t n) {
    int n4 = (int)(n / 4);
    convert_kernel<<<dim3((n4 + 255) / 256), dim3(256), 0, stream>>>(in, out, n4);
  };
  conv(x, x_bf, (size_t)TT * DIM);
  conv(w_q_down, wqd_bf, (size_t)Q_RANK * DIM);
  conv(w_q_up, wqu_bf, (size_t)QD * Q_RANK);
  conv(w_kv_down, wkvd_bf, (size_t)KVD * DIM);
  conv(w_kv_up, wkvu_bf, (size_t)KVUP_D * KV_RANK);
  conv(w_o, wo_bf, (size_t)DIM * DIM);

  dim3 blk(256);
  gemm_bf16_nt<<<dim3(Q_RANK / 64, TT / 64), blk, 0, stream>>>(x_bf, wqd_bf, cq_raw, DIM, DIM, DIM, Q_RANK);
  gemm_bf16_nt<<<dim3(KVD / 64, TT / 64), blk, 0, stream>>>(x_bf, wkvd_bf, kv, DIM, DIM, DIM, KVD);
  rmsnorm_kernel<<<dim3(TT), blk, 0, stream>>>(cq_raw, q_norm_w, cq_bf, Q_RANK, Q_RANK, Q_RANK);
  rmsnorm_kernel<<<dim3(TT), blk, 0, stream>>>(kv, kv_norm_w, ckv_bf, KV_RANK, KVD, KV_RANK);
  gemm_bf16_nt<<<dim3(QD / 64, TT / 64), blk, 0, stream>>>(cq_bf, wqu_bf, qbuf, Q_RANK, Q_RANK, Q_RANK, QD);
  gemm_bf16_nt<<<dim3(KVUP_D / 64, TT / 64), blk, 0, stream>>>(ckv_bf, wkvu_bf, kvup, KV_RANK, KV_RANK, KV_RANK, KVUP_D);
  rope_q_kernel<<<dim3(TT), blk, 0, stream>>>(qbuf, kv, qb_bf, krope_bf);
  conv(kvup, kvup_bf, (size_t)TT * KVUP_D);
  vtrans_kernel<<<dim3(TT / 64, VD / 64, NH), blk, 0, stream>>>(kvup, vtb);
  attn_mfma_kernel<<<dim3(TT / 64, NH), blk, 0, stream>>>(qb_bf, kvup_bf, krope_bf, vtb, attn_bf);
  gemm_bf16_nt<<<dim3(DIM / 64, TT / 64), blk, 0, stream>>>(attn_bf, wo_bf, outp, DIM, DIM, DIM, DIM);
}

// Round 3
// 304.705 us; speedup vs baseline: 3.8346x; 1.1611x over previous
//
#include <hip/hip_runtime.h>
#include <hip/hip_bf16.h>

typedef short short8 __attribute__((ext_vector_type(8)));
typedef float f32x4 __attribute__((ext_vector_type(4)));

#define DIM 2048
#define NH 16
#define KV_RANK 512
#define Q_RANK 1536
#define ROPE_D 64
#define NOPE 128
#define VD 128
#define TT 2048
#define QKH 192                   // NOPE + ROPE
#define QD (NH * QKH)             // 3072
#define KVD (KV_RANK + ROPE_D)    // 576
#define KVUP_D (NH * (NOPE + VD)) // 4096

__device__ inline unsigned short f2bf(float f) {
  __hip_bfloat16 h = __float2bfloat16(f);
  union { __hip_bfloat16 h; unsigned short u; } cv; cv.h = h; return cv.u;
}

__device__ inline void gload_lds16(const void* g, void* l) {
  __builtin_amdgcn_global_load_lds(
      (const __attribute__((address_space(1))) void*)g,
      (__attribute__((address_space(3))) void*)l, 16, 0, 0);
}

// ---------------- fp32 -> bf16 convert (vectorized x4) ----------------
__global__ __launch_bounds__(256) void convert_kernel(const float* __restrict__ in,
                                                      unsigned short* __restrict__ out,
                                                      int n4) {
  int i = blockIdx.x * 256 + threadIdx.x;
  if (i >= n4) return;
  float4 v = reinterpret_cast<const float4*>(in)[i];
  ushort4 o;
  o.x = f2bf(v.x); o.y = f2bf(v.y); o.z = f2bf(v.z); o.w = f2bf(v.w);
  reinterpret_cast<ushort4*>(out)[i] = o;
}

// ------- fast bf16 GEMM (m97 structure): C[M,N] = A[M,K] * W[N,K]^T -------
// grid = (N/128, M/128), block = 256 (4 waves), BK=64, global_load_lds w16,
// source-side pre-swizzle so linear LDS == XOR-swizzled layout (2-way banks).
__global__ __launch_bounds__(256) void gemm_fast(const unsigned short* __restrict__ A,
                                                 const unsigned short* __restrict__ W,
                                                 float* __restrict__ C,
                                                 int K, int lda, int ldb, int ldc) {
  __shared__ __align__(16) unsigned short As[128 * 64];
  __shared__ __align__(16) unsigned short Bs[128 * 64];
  const int tid = threadIdx.x;
  const int bm = blockIdx.y * 128, bn = blockIdx.x * 128;
  const int lane = tid & 63, wave = tid >> 6;
  const int wm = (wave >> 1) * 64, wn = (wave & 1) * 64;
  const int fr = lane & 15, fg = lane >> 4;

  const int sr = lane >> 3;           // sub-row within 8-row chunk
  const int scb = (lane & 7) ^ sr;    // pre-swizzled source col-block
  const int r0 = wave * 32;           // wave's 32-row staging chunk

  f32x4 acc[4][4] = {};

  const unsigned short* Ag = A + (size_t)(bm + r0 + sr) * lda + scb * 8;
  const unsigned short* Wg = W + (size_t)(bn + r0 + sr) * ldb + scb * 8;
  unsigned short* Al = &As[r0 * 64];
  unsigned short* Bl = &Bs[r0 * 64];

  for (int k0 = 0; k0 < K; k0 += 64) {
#pragma unroll
    for (int i = 0; i < 4; ++i) {
      gload_lds16(Ag + (size_t)(i * 8) * lda + k0, Al + i * 8 * 64);
      gload_lds16(Wg + (size_t)(i * 8) * ldb + k0, Bl + i * 8 * 64);
    }
    __syncthreads();
#pragma unroll
    for (int kk = 0; kk < 2; ++kk) {
      short8 a[4], b[4];
#pragma unroll
      for (int i = 0; i < 4; ++i) {
        int ra = wm + i * 16 + fr;
        a[i] = *reinterpret_cast<const short8*>(&As[ra * 64 + (((kk * 4 + fg) ^ (ra & 7)) * 8)]);
        int rb = wn + i * 16 + fr;
        b[i] = *reinterpret_cast<const short8*>(&Bs[rb * 64 + (((kk * 4 + fg) ^ (rb & 7)) * 8)]);
      }
#pragma unroll
      for (int i = 0; i < 4; ++i)
#pragma unroll
        for (int j = 0; j < 4; ++j)
          acc[i][j] = __builtin_amdgcn_mfma_f32_16x16x32_bf16(a[i], b[j], acc[i][j], 0, 0, 0);
    }
    __syncthreads();
  }
#pragma unroll
  for (int i = 0; i < 4; ++i) {
    int row0 = bm + wm + i * 16 + fg * 4;
#pragma unroll
    for (int j = 0; j < 4; ++j) {
      int col = bn + wn + j * 16 + fr;
#pragma unroll
      for (int r = 0; r < 4; ++r)
        C[(size_t)(row0 + r) * ldc + col] = acc[i][j][r];
    }
  }
}

// ---------------- small bf16 GEMM (64x64 tile) for N%128 != 0 ----------------
__global__ __launch_bounds__(256) void gemm_bf16_nt(const unsigned short* __restrict__ A,
                                                    const unsigned short* __restrict__ W,
                                                    float* __restrict__ C,
                                                    int K, int lda, int ldb, int ldc) {
  __shared__ __align__(16) unsigned short As[64 * 32];
  __shared__ __align__(16) unsigned short Ws[64 * 32];
  const int tid = threadIdx.x;
  const int bm = blockIdx.y * 64, bn = blockIdx.x * 64;
  const int lane = tid & 63, wave = tid >> 6;
  const int wm = (wave >> 1) * 32, wn = (wave & 1) * 32;
  const int srow = tid >> 2, scb = tid & 3;
  const int fr = lane & 15, fkb = lane >> 4;

  f32x4 acc[2][2] = {};

  const unsigned short* Ap = A + (size_t)(bm + srow) * lda + scb * 8;
  const unsigned short* Wp = W + (size_t)(bn + srow) * ldb + scb * 8;
  const int st = srow * 32 + ((scb ^ (srow & 3)) * 8);

  for (int k0 = 0; k0 < K; k0 += 32) {
    uint4 av = *reinterpret_cast<const uint4*>(Ap); Ap += 32;
    uint4 wv = *reinterpret_cast<const uint4*>(Wp); Wp += 32;
    *reinterpret_cast<uint4*>(&As[st]) = av;
    *reinterpret_cast<uint4*>(&Ws[st]) = wv;
    __syncthreads();
    short8 a[2], b[2];
#pragma unroll
    for (int i = 0; i < 2; ++i) {
      int ra = wm + i * 16 + fr;
      a[i] = *reinterpret_cast<const short8*>(&As[ra * 32 + ((fkb ^ (ra & 3)) * 8)]);
      int rb = wn + i * 16 + fr;
      b[i] = *reinterpret_cast<const short8*>(&Ws[rb * 32 + ((fkb ^ (rb & 3)) * 8)]);
    }
    acc[0][0] = __builtin_amdgcn_mfma_f32_16x16x32_bf16(a[0], b[0], acc[0][0], 0, 0, 0);
    acc[0][1] = __builtin_amdgcn_mfma_f32_16x16x32_bf16(a[0], b[1], acc[0][1], 0, 0, 0);
    acc[1][0] = __builtin_amdgcn_mfma_f32_16x16x32_bf16(a[1], b[0], acc[1][0], 0, 0, 0);
    acc[1][1] = __builtin_amdgcn_mfma_f32_16x16x32_bf16(a[1], b[1], acc[1][1], 0, 0, 0);
    __syncthreads();
  }
#pragma unroll
  for (int i = 0; i < 2; ++i)
#pragma unroll
    for (int j = 0; j < 2; ++j) {
      int row0 = bm + wm + i * 16 + (lane >> 4) * 4;
      int col = bn + wn + j * 16 + (lane & 15);
#pragma unroll
      for (int r = 0; r < 4; ++r)
        C[(size_t)(row0 + r) * ldc + col] = acc[i][j][r];
    }
}

// ---------------- RMSNorm rows: fp32 in -> bf16 out -------------------
__global__ __launch_bounds__(256) void rmsnorm_kernel(const float* __restrict__ in,
                                                      const float* __restrict__ w,
                                                      unsigned short* __restrict__ out,
                                                      int cols, int in_stride, int out_stride) {
  const int row = blockIdx.x, tid = threadIdx.x;
  const float* x = in + (size_t)row * in_stride;
  float ss = 0.f;
  for (int c = tid; c < cols; c += 256) { float v = x[c]; ss += v * v; }
  __shared__ float red[256];
  red[tid] = ss; __syncthreads();
  for (int off = 128; off > 0; off >>= 1) {
    if (tid < off) red[tid] += red[tid + off];
    __syncthreads();
  }
  float r = rsqrtf(red[0] / (float)cols + 1e-6f);
  for (int c = tid; c < cols; c += 256)
    out[(size_t)row * out_stride + c] = f2bf(x[c] * r * w[c]);
}

// ------- RoPE on q (fp32 -> bf16 full row) + k_rope extraction (bf16) -------
__global__ __launch_bounds__(256) void rope_q_kernel(const float* __restrict__ q,
                                                     const float* __restrict__ kv,
                                                     unsigned short* __restrict__ qb,
                                                     unsigned short* __restrict__ kr) {
  const int t = blockIdx.x, tid = threadIdx.x;
  const float* qrow = q + (size_t)t * QD;
  unsigned short* qorow = qb + (size_t)t * QD;
  for (int i = tid; i < NH * NOPE; i += 256) {
    int h = i >> 7, c = i & 127;
    qorow[h * QKH + c] = f2bf(qrow[h * QKH + c]);
  }
  for (int p = tid; p < NH * 32 + 32; p += 256) {
    int j = (p < NH * 32) ? (p & 31) : (p - NH * 32);
    float inv = powf(500000.0f, -(float)(2 * j) * (1.0f / 64.0f));
    float ang = (float)t * inv;
    float sv, cv;
    sincosf(ang, &sv, &cv);
    if (p < NH * 32) {
      int h = p >> 5;
      const float* b = qrow + h * QKH + NOPE + 2 * j;
      float e = b[0], o = b[1];
      qorow[h * QKH + NOPE + 2 * j]     = f2bf(e * cv - o * sv);
      qorow[h * QKH + NOPE + 2 * j + 1] = f2bf(o * cv + e * sv);
    } else {
      const float* b = kv + (size_t)t * KVD + KV_RANK + 2 * j;
      float e = b[0], o = b[1];
      kr[(size_t)t * ROPE_D + 2 * j]     = f2bf(e * cv - o * sv);
      kr[(size_t)t * ROPE_D + 2 * j + 1] = f2bf(o * cv + e * sv);
    }
  }
}

// ------- V^T: vt[h*128+d][t] = bf16(kvup[t][h*256+128+d]) -------
__global__ __launch_bounds__(256) void vtrans_kernel(const float* __restrict__ kvup,
                                                     unsigned short* __restrict__ vt) {
  __shared__ unsigned short tile[64][65];
  const int h = blockIdx.z;
  const int t0 = blockIdx.x * 64;
  const int d0 = blockIdx.y * 64;
  const int tid = threadIdx.x;
  const int r = tid >> 2, cb = tid & 3;
  const float* src = kvup + (size_t)(t0 + r) * KVUP_D + h * 256 + NOPE + d0 + cb * 16;
#pragma unroll
  for (int e = 0; e < 16; e += 4) {
    float4 v = *reinterpret_cast<const float4*>(src + e);
    tile[r][cb * 16 + e]     = f2bf(v.x);
    tile[r][cb * 16 + e + 1] = f2bf(v.y);
    tile[r][cb * 16 + e + 2] = f2bf(v.z);
    tile[r][cb * 16 + e + 3] = f2bf(v.w);
  }
  __syncthreads();
  unsigned short* dst = vt + (size_t)(h * VD + d0 + r) * TT + t0 + cb * 16;
#pragma unroll
  for (int e = 0; e < 16; e += 4) {
    ushort4 w;
    w.x = tile[cb * 16 + e + 0][r];
    w.y = tile[cb * 16 + e + 1][r];
    w.z = tile[cb * 16 + e + 2][r];
    w.w = tile[cb * 16 + e + 3][r];
    *reinterpret_cast<ushort4*>(dst + e) = w;
  }
}

// ---------------- MFMA flash attention, paired causal tiles ----------------
// grid = (16, H), block = 512 (8 waves). Waves 0-3 own q-tile px (rows px*64..),
// waves 4-7 own q-tile 31-px. K/V staged once per k-tile, shared by both.
// All LDS XOR-swizzled: elem ^= (row&7)<<3  (16B granularity).
__global__ __launch_bounds__(512) void attn_mfma_kernel(
    const unsigned short* __restrict__ qb,     // [T][3072] bf16 (rope applied)
    const unsigned short* __restrict__ kvupb,  // [T][4096] bf16
    const unsigned short* __restrict__ kropeb, // [T][64] bf16
    const unsigned short* __restrict__ vtb,    // [H*128][T] bf16
    unsigned short* __restrict__ out)          // [T][2048] bf16
{
  const int h = blockIdx.y;
  const int px = blockIdx.x;
  const int qa = px, qbt = 31 - px;
  const int tid = threadIdx.x;
  const int lane = tid & 63, wave = tid >> 6;
  const int w4 = wave & 3;
  const int myq = (wave < 4) ? qa : qbt;
  const int t0 = myq * 64;
  const int fr = lane & 15, fg = lane >> 4;

  __shared__ __align__(16) unsigned short Ks[64 * 192];
  __shared__ __align__(16) unsigned short Vs[128 * 64];
  __shared__ __align__(16) unsigned short Ps[8][16 * 64];

  // Q fragments: A-frag row = fr, k = kc*32 + fg*8 + e
  short8 qf[6];
  {
    const unsigned short* qrow = qb + (size_t)(t0 + w4 * 16 + fr) * QD + h * QKH;
#pragma unroll
    for (int kc = 0; kc < 6; ++kc)
      qf[kc] = *reinterpret_cast<const short8*>(qrow + kc * 32 + fg * 8);
  }

  f32x4 o[8] = {};
  float m[4] = {-1e30f, -1e30f, -1e30f, -1e30f};
  float l[4] = {0.f, 0.f, 0.f, 0.f};
  const float scale = 0.0721687836487032f;  // 1/sqrt(192)

  const int nkt = qbt + 1;
  for (int kt = 0; kt < nkt; ++kt) {
    const int kt0 = kt * 64;
    // stage K (64 rows x 192 elems: 24 col-blocks of 8), swizzled
#pragma unroll
    for (int i = 0; i < 3; ++i) {
      int u = tid + i * 512;
      int row = u / 24, cb = u - row * 24;
      const unsigned short* src = (cb < 16)
        ? kvupb + (size_t)(kt0 + row) * KVUP_D + h * 256 + cb * 8
        : kropeb + (size_t)(kt0 + row) * ROPE_D + (cb - 16) * 8;
      *reinterpret_cast<uint4*>(&Ks[row * 192 + ((cb ^ (row & 7)) * 8)]) =
        *reinterpret_cast<const uint4*>(src);
    }
    // stage V^T (128 d-rows x 64 keys: 8 col-blocks), swizzled
#pragma unroll
    for (int i = 0; i < 2; ++i) {
      int u = tid + i * 512;
      int d = u >> 3, cb = u & 7;
      *reinterpret_cast<uint4*>(&Vs[d * 64 + ((cb ^ (d & 7)) * 8)]) =
        *reinterpret_cast<const uint4*>(vtb + (size_t)(h * VD + d) * TT + kt0 + cb * 8);
    }
    __syncthreads();

    if (kt <= myq) {
      // S = Q K^T : 16 x 64 per wave
      f32x4 s[4] = {};
#pragma unroll
      for (int kc = 0; kc < 6; ++kc) {
#pragma unroll
        for (int j = 0; j < 4; ++j) {
          int rb = j * 16 + fr;
          short8 b = *reinterpret_cast<const short8*>(
              &Ks[rb * 192 + (((kc * 4 + fg) ^ (rb & 7)) * 8)]);
          s[j] = __builtin_amdgcn_mfma_f32_16x16x32_bf16(qf[kc], b, s[j], 0, 0, 0);
        }
      }

      const bool diag = (kt == myq);
#pragma unroll
      for (int r = 0; r < 4; ++r) {
        float sv[4];
#pragma unroll
        for (int j = 0; j < 4; ++j) {
          float x = s[j][r] * scale;
          if (diag && (j * 16 + fr) > (w4 * 16 + fg * 4 + r)) x = -1e30f;
          sv[j] = x;
        }
        float mx = fmaxf(fmaxf(sv[0], sv[1]), fmaxf(sv[2], sv[3]));
#pragma unroll
        for (int off = 1; off < 16; off <<= 1)
          mx = fmaxf(mx, __shfl_xor(mx, off));
        float mn = fmaxf(m[r], mx);
        float corr = __expf(m[r] - mn);
        m[r] = mn;
        float ssum = 0.f;
        float p[4];
#pragma unroll
        for (int j = 0; j < 4; ++j) {
          p[j] = __expf(sv[j] - mn);
          ssum += p[j];
        }
#pragma unroll
        for (int off = 1; off < 16; off <<= 1)
          ssum += __shfl_xor(ssum, off);
        l[r] = l[r] * corr + ssum;
#pragma unroll
        for (int dj = 0; dj < 8; ++dj) o[dj][r] *= corr;
        int prow = fg * 4 + r;
#pragma unroll
        for (int j = 0; j < 4; ++j)
          Ps[wave][prow * 64 + ((j * 16 + fr) ^ ((prow & 7) << 3))] = f2bf(p[j]);
      }

      // O += P V
#pragma unroll
      for (int kc = 0; kc < 2; ++kc) {
        short8 p = *reinterpret_cast<const short8*>(
            &Ps[wave][fr * 64 + (((kc * 4 + fg) ^ (fr & 7)) * 8)]);
#pragma unroll
        for (int dj = 0; dj < 8; ++dj) {
          int rv = dj * 16 + fr;
          short8 b = *reinterpret_cast<const short8*>(
              &Vs[rv * 64 + (((kc * 4 + fg) ^ (rv & 7)) * 8)]);
          o[dj] = __builtin_amdgcn_mfma_f32_16x16x32_bf16(p, b, o[dj], 0, 0, 0);
        }
      }
    }
    __syncthreads();
  }

#pragma unroll
  for (int r = 0; r < 4; ++r) {
    float linv = 1.0f / l[r];
    int trow = t0 + w4 * 16 + fg * 4 + r;
    unsigned short* orow = out + (size_t)trow * DIM + h * VD;
#pragma unroll
    for (int dj = 0; dj < 8; ++dj)
      orow[dj * 16 + fr] = f2bf(o[dj][r] * linv);
  }
}

// ---------------- launch ----------------
extern "C" void kernel_launch(void* const* d_in, const int* in_sizes, int n_in,
                              void* d_out, int out_size, void* d_ws, size_t ws_size,
                              hipStream_t stream) {
  const float* x        = (const float*)d_in[0];
  const float* w_q_down = (const float*)d_in[1];
  const float* q_norm_w = (const float*)d_in[2];
  const float* w_q_up   = (const float*)d_in[3];
  const float* w_kv_down= (const float*)d_in[4];
  const float* kv_norm_w= (const float*)d_in[5];
  const float* w_kv_up  = (const float*)d_in[6];
  const float* w_o      = (const float*)d_in[7];
  float* outp = (float*)d_out;

  char* ws = (char*)d_ws;
  size_t off = 0;
  auto alloc = [&](size_t bytes) {
    void* p = ws + off;
    off += (bytes + 255) & ~(size_t)255;
    return p;
  };
  float* cq_raw = (float*)alloc((size_t)TT * Q_RANK * 4);   // reused for vtb
  float* kv     = (float*)alloc((size_t)TT * KVD * 4);
  float* qbuf   = (float*)alloc((size_t)TT * QD * 4);
  float* kvup   = (float*)alloc((size_t)TT * KVUP_D * 4);
  unsigned short* x_bf    = (unsigned short*)alloc((size_t)TT * DIM * 2);  // reused for attn_bf
  unsigned short* wqd_bf  = (unsigned short*)alloc((size_t)Q_RANK * DIM * 2);
  unsigned short* wqu_bf  = (unsigned short*)alloc((size_t)QD * Q_RANK * 2);
  unsigned short* wkvd_bf = (unsigned short*)alloc((size_t)KVD * DIM * 2);
  unsigned short* wkvu_bf = (unsigned short*)alloc((size_t)KVUP_D * KV_RANK * 2);
  unsigned short* wo_bf   = (unsigned short*)alloc((size_t)DIM * DIM * 2);
  unsigned short* cq_bf   = (unsigned short*)alloc((size_t)TT * Q_RANK * 2);
  unsigned short* ckv_bf  = (unsigned short*)alloc((size_t)TT * KV_RANK * 2);
  unsigned short* qb_bf   = (unsigned short*)alloc((size_t)TT * QD * 2);
  unsigned short* kvup_bf = (unsigned short*)alloc((size_t)TT * KVUP_D * 2);
  unsigned short* krope_bf= (unsigned short*)alloc((size_t)TT * ROPE_D * 2);
  unsigned short* vtb     = (unsigned short*)cq_raw;  // [H*128][T] bf16 = 8.4MB < 12.6MB
  unsigned short* attn_bf = x_bf;                     // [T][2048] bf16, x_bf dead by then

  auto conv = [&](const float* in, unsigned short* out, size_t n) {
    int n4 = (int)(n / 4);
    convert_kernel<<<dim3((n4 + 255) / 256), dim3(256), 0, stream>>>(in, out, n4);
  };
  conv(x, x_bf, (size_t)TT * DIM);
  conv(w_q_down, wqd_bf, (size_t)Q_RANK * DIM);
  conv(w_q_up, wqu_bf, (size_t)QD * Q_RANK);
  conv(w_kv_down, wkvd_bf, (size_t)KVD * DIM);
  conv(w_kv_up, wkvu_bf, (size_t)KVUP_D * KV_RANK);
  conv(w_o, wo_bf, (size_t)DIM * DIM);

  dim3 blk(256);
  // cq_raw = x @ w_q_down^T   [2048 x 1536], K=2048
  gemm_fast<<<dim3(Q_RANK / 128, TT / 128), blk, 0, stream>>>(x_bf, wqd_bf, cq_raw, DIM, DIM, DIM, Q_RANK);
  // kv = x @ w_kv_down^T      [2048 x 576], K=2048 (N not /128 -> small gemm)
  gemm_bf16_nt<<<dim3(KVD / 64, TT / 64), blk, 0, stream>>>(x_bf, wkvd_bf, kv, DIM, DIM, DIM, KVD);
  rmsnorm_kernel<<<dim3(TT), blk, 0, stream>>>(cq_raw, q_norm_w, cq_bf, Q_RANK, Q_RANK, Q_RANK);
  rmsnorm_kernel<<<dim3(TT), blk, 0, stream>>>(kv, kv_norm_w, ckv_bf, KV_RANK, KVD, KV_RANK);
  // q = c_q @ w_q_up^T        [2048 x 3072], K=1536
  gemm_fast<<<dim3(QD / 128, TT / 128), blk, 0, stream>>>(cq_bf, wqu_bf, qbuf, Q_RANK, Q_RANK, Q_RANK, QD);
  // kv_up = c_kv @ w_kv_up^T  [2048 x 4096], K=512
  gemm_fast<<<dim3(KVUP_D / 128, TT / 128), blk, 0, stream>>>(ckv_bf, wkvu_bf, kvup, KV_RANK, KV_RANK, KV_RANK, KVUP_D);
  rope_q_kernel<<<dim3(TT), blk, 0, stream>>>(qbuf, kv, qb_bf, krope_bf);
  conv(kvup, kvup_bf, (size_t)TT * KVUP_D);
  vtrans_kernel<<<dim3(TT / 64, VD / 64, NH), blk, 0, stream>>>(kvup, vtb);
  attn_mfma_kernel<<<dim3(16, NH), dim3(512), 0, stream>>>(qb_bf, kvup_bf, krope_bf, vtb, attn_bf);
  // out = attn @ w_o^T        [2048 x 2048], K=2048
  gemm_fast<<<dim3(DIM / 128, TT / 128), blk, 0, stream>>>(attn_bf, wo_bf, outp, DIM, DIM, DIM, DIM);
}

// Round 4
// 282.896 us; speedup vs baseline: 4.1302x; 1.0771x over previous
//
#include <hip/hip_runtime.h>
#include <hip/hip_bf16.h>

typedef short short8 __attribute__((ext_vector_type(8)));
typedef float f32x4 __attribute__((ext_vector_type(4)));

#define DIM 2048
#define NH 16
#define KV_RANK 512
#define Q_RANK 1536
#define ROPE_D 64
#define NOPE 128
#define VD 128
#define TT 2048
#define QKH 192                   // NOPE + ROPE
#define QD (NH * QKH)             // 3072
#define KVD (KV_RANK + ROPE_D)    // 576
#define KVUP_D (NH * (NOPE + VD)) // 4096

__device__ inline unsigned short f2bf(float f) {
  __hip_bfloat16 h = __float2bfloat16(f);
  union { __hip_bfloat16 h; unsigned short u; } cv; cv.h = h; return cv.u;
}
__device__ inline float bf2f(unsigned short u) {
  union { unsigned int i; float f; } cv; cv.i = ((unsigned int)u) << 16; return cv.f;
}

__device__ inline void gload_lds16(const void* g, void* l) {
  __builtin_amdgcn_global_load_lds(
      (const __attribute__((address_space(1))) void*)g,
      (__attribute__((address_space(3))) void*)l, 16, 0, 0);
}

// -------- batched fp32 -> bf16 convert over 6 buffers, one launch --------
__global__ __launch_bounds__(256) void convert6_kernel(
    const float* s0, const float* s1, const float* s2, const float* s3,
    const float* s4, const float* s5,
    unsigned short* d0, unsigned short* d1, unsigned short* d2,
    unsigned short* d3, unsigned short* d4, unsigned short* d5,
    int n0, int n1, int n2, int n3, int n4c, int n5) {
  int i = blockIdx.x * 256 + threadIdx.x;
  const float* src;
  unsigned short* dst;
  if (i < n0) { src = s0; dst = d0; }
  else if ((i -= n0) < n1) { src = s1; dst = d1; }
  else if ((i -= n1) < n2) { src = s2; dst = d2; }
  else if ((i -= n2) < n3) { src = s3; dst = d3; }
  else if ((i -= n3) < n4c) { src = s4; dst = d4; }
  else if ((i -= n4c) < n5) { src = s5; dst = d5; }
  else return;
  float4 v = reinterpret_cast<const float4*>(src)[i];
  ushort4 o;
  o.x = f2bf(v.x); o.y = f2bf(v.y); o.z = f2bf(v.z); o.w = f2bf(v.w);
  reinterpret_cast<ushort4*>(dst)[i] = o;
}

// ------- fast bf16 GEMM (m97 structure): C[M,N] = A[M,K] * W[N,K]^T -------
// grid = (N/128, M/128), block = 256 (4 waves), BK=64, global_load_lds w16.
// If Cb != nullptr, writes bf16 to Cb, else fp32 to Cf.
__global__ __launch_bounds__(256) void gemm_fast(const unsigned short* __restrict__ A,
                                                 const unsigned short* __restrict__ W,
                                                 float* __restrict__ Cf,
                                                 unsigned short* __restrict__ Cb,
                                                 int K, int lda, int ldb, int ldc) {
  __shared__ __align__(16) unsigned short As[128 * 64];
  __shared__ __align__(16) unsigned short Bs[128 * 64];
  const int tid = threadIdx.x;
  const int bm = blockIdx.y * 128, bn = blockIdx.x * 128;
  const int lane = tid & 63, wave = tid >> 6;
  const int wm = (wave >> 1) * 64, wn = (wave & 1) * 64;
  const int fr = lane & 15, fg = lane >> 4;

  const int sr = lane >> 3;           // sub-row within 8-row chunk
  const int scb = (lane & 7) ^ sr;    // pre-swizzled source col-block
  const int r0 = wave * 32;           // wave's 32-row staging chunk

  f32x4 acc[4][4] = {};

  const unsigned short* Ag = A + (size_t)(bm + r0 + sr) * lda + scb * 8;
  const unsigned short* Wg = W + (size_t)(bn + r0 + sr) * ldb + scb * 8;
  unsigned short* Al = &As[r0 * 64];
  unsigned short* Bl = &Bs[r0 * 64];

  for (int k0 = 0; k0 < K; k0 += 64) {
#pragma unroll
    for (int i = 0; i < 4; ++i) {
      gload_lds16(Ag + (size_t)(i * 8) * lda + k0, Al + i * 8 * 64);
      gload_lds16(Wg + (size_t)(i * 8) * ldb + k0, Bl + i * 8 * 64);
    }
    __syncthreads();
#pragma unroll
    for (int kk = 0; kk < 2; ++kk) {
      short8 a[4], b[4];
#pragma unroll
      for (int i = 0; i < 4; ++i) {
        int ra = wm + i * 16 + fr;
        a[i] = *reinterpret_cast<const short8*>(&As[ra * 64 + (((kk * 4 + fg) ^ (ra & 7)) * 8)]);
        int rb = wn + i * 16 + fr;
        b[i] = *reinterpret_cast<const short8*>(&Bs[rb * 64 + (((kk * 4 + fg) ^ (rb & 7)) * 8)]);
      }
#pragma unroll
      for (int i = 0; i < 4; ++i)
#pragma unroll
        for (int j = 0; j < 4; ++j)
          acc[i][j] = __builtin_amdgcn_mfma_f32_16x16x32_bf16(a[i], b[j], acc[i][j], 0, 0, 0);
    }
    __syncthreads();
  }
  if (Cb) {
#pragma unroll
    for (int i = 0; i < 4; ++i) {
      int row0 = bm + wm + i * 16 + fg * 4;
#pragma unroll
      for (int j = 0; j < 4; ++j) {
        int col = bn + wn + j * 16 + fr;
#pragma unroll
        for (int r = 0; r < 4; ++r)
          Cb[(size_t)(row0 + r) * ldc + col] = f2bf(acc[i][j][r]);
      }
    }
  } else {
#pragma unroll
    for (int i = 0; i < 4; ++i) {
      int row0 = bm + wm + i * 16 + fg * 4;
#pragma unroll
      for (int j = 0; j < 4; ++j) {
        int col = bn + wn + j * 16 + fr;
#pragma unroll
        for (int r = 0; r < 4; ++r)
          Cf[(size_t)(row0 + r) * ldc + col] = acc[i][j][r];
      }
    }
  }
}

// ---------------- small bf16 GEMM (64x64 tile) for N%128 != 0 ----------------
__global__ __launch_bounds__(256) void gemm_bf16_nt(const unsigned short* __restrict__ A,
                                                    const unsigned short* __restrict__ W,
                                                    float* __restrict__ C,
                                                    int K, int lda, int ldb, int ldc) {
  __shared__ __align__(16) unsigned short As[64 * 32];
  __shared__ __align__(16) unsigned short Ws[64 * 32];
  const int tid = threadIdx.x;
  const int bm = blockIdx.y * 64, bn = blockIdx.x * 64;
  const int lane = tid & 63, wave = tid >> 6;
  const int wm = (wave >> 1) * 32, wn = (wave & 1) * 32;
  const int srow = tid >> 2, scb = tid & 3;
  const int fr = lane & 15, fkb = lane >> 4;

  f32x4 acc[2][2] = {};

  const unsigned short* Ap = A + (size_t)(bm + srow) * lda + scb * 8;
  const unsigned short* Wp = W + (size_t)(bn + srow) * ldb + scb * 8;
  const int st = srow * 32 + ((scb ^ (srow & 3)) * 8);

  for (int k0 = 0; k0 < K; k0 += 32) {
    uint4 av = *reinterpret_cast<const uint4*>(Ap); Ap += 32;
    uint4 wv = *reinterpret_cast<const uint4*>(Wp); Wp += 32;
    *reinterpret_cast<uint4*>(&As[st]) = av;
    *reinterpret_cast<uint4*>(&Ws[st]) = wv;
    __syncthreads();
    short8 a[2], b[2];
#pragma unroll
    for (int i = 0; i < 2; ++i) {
      int ra = wm + i * 16 + fr;
      a[i] = *reinterpret_cast<const short8*>(&As[ra * 32 + ((fkb ^ (ra & 3)) * 8)]);
      int rb = wn + i * 16 + fr;
      b[i] = *reinterpret_cast<const short8*>(&Ws[rb * 32 + ((fkb ^ (rb & 3)) * 8)]);
    }
    acc[0][0] = __builtin_amdgcn_mfma_f32_16x16x32_bf16(a[0], b[0], acc[0][0], 0, 0, 0);
    acc[0][1] = __builtin_amdgcn_mfma_f32_16x16x32_bf16(a[0], b[1], acc[0][1], 0, 0, 0);
    acc[1][0] = __builtin_amdgcn_mfma_f32_16x16x32_bf16(a[1], b[0], acc[1][0], 0, 0, 0);
    acc[1][1] = __builtin_amdgcn_mfma_f32_16x16x32_bf16(a[1], b[1], acc[1][1], 0, 0, 0);
    __syncthreads();
  }
#pragma unroll
  for (int i = 0; i < 2; ++i)
#pragma unroll
    for (int j = 0; j < 2; ++j) {
      int row0 = bm + wm + i * 16 + (lane >> 4) * 4;
      int col = bn + wn + j * 16 + (lane & 15);
#pragma unroll
      for (int r = 0; r < 4; ++r)
        C[(size_t)(row0 + r) * ldc + col] = acc[i][j][r];
    }
}

// ------- RMSNorm rows, fp32 input -------
__global__ __launch_bounds__(256) void rmsnorm_f32(const float* __restrict__ in,
                                                   const float* __restrict__ w,
                                                   unsigned short* __restrict__ out,
                                                   int cols, int in_stride, int out_stride) {
  const int row = blockIdx.x, tid = threadIdx.x;
  const float* x = in + (size_t)row * in_stride;
  float ss = 0.f;
  for (int c = tid; c < cols; c += 256) { float v = x[c]; ss += v * v; }
  __shared__ float red[256];
  red[tid] = ss; __syncthreads();
  for (int off = 128; off > 0; off >>= 1) {
    if (tid < off) red[tid] += red[tid + off];
    __syncthreads();
  }
  float r = rsqrtf(red[0] / (float)cols + 1e-6f);
  for (int c = tid; c < cols; c += 256)
    out[(size_t)row * out_stride + c] = f2bf(x[c] * r * w[c]);
}

// ------- RMSNorm rows, bf16 input (vectorized short8) -------
__global__ __launch_bounds__(256) void rmsnorm_bf16(const unsigned short* __restrict__ in,
                                                    const float* __restrict__ w,
                                                    unsigned short* __restrict__ out,
                                                    int cols) {
  const int row = blockIdx.x, tid = threadIdx.x;
  const unsigned short* x = in + (size_t)row * cols;
  const int nch = cols >> 3;
  float ss = 0.f;
  for (int cb = tid; cb < nch; cb += 256) {
    short8 v = *reinterpret_cast<const short8*>(x + cb * 8);
#pragma unroll
    for (int e = 0; e < 8; ++e) { float f = bf2f((unsigned short)v[e]); ss += f * f; }
  }
  __shared__ float red[256];
  red[tid] = ss; __syncthreads();
  for (int off = 128; off > 0; off >>= 1) {
    if (tid < off) red[tid] += red[tid + off];
    __syncthreads();
  }
  float r = rsqrtf(red[0] / (float)cols + 1e-6f);
  for (int cb = tid; cb < nch; cb += 256) {
    short8 v = *reinterpret_cast<const short8*>(x + cb * 8);
    ushort4 o0, o1;
    o0.x = f2bf(bf2f((unsigned short)v[0]) * r * w[cb * 8 + 0]);
    o0.y = f2bf(bf2f((unsigned short)v[1]) * r * w[cb * 8 + 1]);
    o0.z = f2bf(bf2f((unsigned short)v[2]) * r * w[cb * 8 + 2]);
    o0.w = f2bf(bf2f((unsigned short)v[3]) * r * w[cb * 8 + 3]);
    o1.x = f2bf(bf2f((unsigned short)v[4]) * r * w[cb * 8 + 4]);
    o1.y = f2bf(bf2f((unsigned short)v[5]) * r * w[cb * 8 + 5]);
    o1.z = f2bf(bf2f((unsigned short)v[6]) * r * w[cb * 8 + 6]);
    o1.w = f2bf(bf2f((unsigned short)v[7]) * r * w[cb * 8 + 7]);
    *reinterpret_cast<ushort4*>(out + (size_t)row * cols + cb * 8) = o0;
    *reinterpret_cast<ushort4*>(out + (size_t)row * cols + cb * 8 + 4) = o1;
  }
}

// ------- RoPE in-place on bf16 q rows + k_rope extraction (bf16) -------
__global__ __launch_bounds__(256) void rope_kernel(unsigned short* __restrict__ qb,
                                                   const float* __restrict__ kv,
                                                   unsigned short* __restrict__ kr) {
  const int t = blockIdx.x, tid = threadIdx.x;
  unsigned short* qrow = qb + (size_t)t * QD;
  for (int p = tid; p < NH * 32 + 32; p += 256) {
    int j = (p < NH * 32) ? (p & 31) : (p - NH * 32);
    float inv = powf(500000.0f, -(float)(2 * j) * (1.0f / 64.0f));
    float ang = (float)t * inv;
    float sv, cv;
    sincosf(ang, &sv, &cv);
    if (p < NH * 32) {
      int h = p >> 5;
      unsigned short* b = qrow + h * QKH + NOPE + 2 * j;
      float e = bf2f(b[0]), o = bf2f(b[1]);
      b[0] = f2bf(e * cv - o * sv);
      b[1] = f2bf(o * cv + e * sv);
    } else {
      const float* b = kv + (size_t)t * KVD + KV_RANK + 2 * j;
      float e = b[0], o = b[1];
      kr[(size_t)t * ROPE_D + 2 * j]     = f2bf(e * cv - o * sv);
      kr[(size_t)t * ROPE_D + 2 * j + 1] = f2bf(o * cv + e * sv);
    }
  }
}

// ------- V^T from bf16 kvup: vt[h*128+d][t] = kvupb[t][h*256+128+d] -------
__global__ __launch_bounds__(256) void vtrans_kernel(const unsigned short* __restrict__ kvupb,
                                                     unsigned short* __restrict__ vt) {
  __shared__ unsigned short tile[64][65];
  const int h = blockIdx.z;
  const int t0 = blockIdx.x * 64;
  const int d0 = blockIdx.y * 64;
  const int tid = threadIdx.x;
  const int r = tid >> 2, cb = tid & 3;
  const unsigned short* src = kvupb + (size_t)(t0 + r) * KVUP_D + h * 256 + NOPE + d0 + cb * 16;
#pragma unroll
  for (int e = 0; e < 16; e += 8) {
    short8 v = *reinterpret_cast<const short8*>(src + e);
#pragma unroll
    for (int q = 0; q < 8; ++q) tile[r][cb * 16 + e + q] = (unsigned short)v[q];
  }
  __syncthreads();
  unsigned short* dst = vt + (size_t)(h * VD + d0 + r) * TT + t0 + cb * 16;
#pragma unroll
  for (int e = 0; e < 16; e += 4) {
    ushort4 w;
    w.x = tile[cb * 16 + e + 0][r];
    w.y = tile[cb * 16 + e + 1][r];
    w.z = tile[cb * 16 + e + 2][r];
    w.w = tile[cb * 16 + e + 3][r];
    *reinterpret_cast<ushort4*>(dst + e) = w;
  }
}

// ---------------- MFMA flash attention, 4-wave blocks ----------------
// grid = 512 (1D), block = 256 (4 waves). Block u: h = u&15,
// qi = (u<256) ? 16+(u>>4) : 15-((u-256)>>4)  -> co-resident pairs sum to 33 iters.
// All LDS XOR-swizzled: cb ^= row&7 (16B granularity).
__global__ __launch_bounds__(256) void attn_mfma_kernel(
    const unsigned short* __restrict__ qb,     // [T][3072] bf16 (rope applied)
    const unsigned short* __restrict__ kvupb,  // [T][4096] bf16
    const unsigned short* __restrict__ kropeb, // [T][64] bf16
    const unsigned short* __restrict__ vtb,    // [H*128][T] bf16
    unsigned short* __restrict__ out)          // [T][2048] bf16
{
  const int u = blockIdx.x;
  const int h = u & 15;
  const int j15 = (u & 255) >> 4;
  const int qi = (u < 256) ? (16 + j15) : (15 - j15);
  const int t0 = qi * 64;
  const int tid = threadIdx.x;
  const int lane = tid & 63, wave = tid >> 6;
  const int fr = lane & 15, fg = lane >> 4;

  __shared__ __align__(16) unsigned short Ks[64 * 192];
  __shared__ __align__(16) unsigned short Vs[128 * 64];
  __shared__ __align__(16) unsigned short Ps[4][16 * 64];

  // Q fragments: A-frag row = fr, k = kc*32 + fg*8 + e
  short8 qf[6];
  {
    const unsigned short* qrow = qb + (size_t)(t0 + wave * 16 + fr) * QD + h * QKH;
#pragma unroll
    for (int kc = 0; kc < 6; ++kc)
      qf[kc] = *reinterpret_cast<const short8*>(qrow + kc * 32 + fg * 8);
  }

  f32x4 o[8] = {};
  float m[4] = {-1e30f, -1e30f, -1e30f, -1e30f};
  float l[4] = {0.f, 0.f, 0.f, 0.f};
  const float scale = 0.0721687836487032f;  // 1/sqrt(192)

  const int nkt = qi + 1;
  for (int kt = 0; kt < nkt; ++kt) {
    const int kt0 = kt * 64;
    // stage K (64 rows x 24 col-blocks of 8 elems), swizzled
#pragma unroll
    for (int i = 0; i < 6; ++i) {
      int c = tid + i * 256;
      int row = c / 24, cb = c - (c / 24) * 24;
      const unsigned short* src = (cb < 16)
        ? kvupb + (size_t)(kt0 + row) * KVUP_D + h * 256 + cb * 8
        : kropeb + (size_t)(kt0 + row) * ROPE_D + (cb - 16) * 8;
      *reinterpret_cast<uint4*>(&Ks[row * 192 + ((cb ^ (row & 7)) * 8)]) =
        *reinterpret_cast<const uint4*>(src);
    }
    // stage V^T (128 d-rows x 8 col-blocks), swizzled
#pragma unroll
    for (int i = 0; i < 4; ++i) {
      int c = tid + i * 256;
      int d = c >> 3, cb = c & 7;
      *reinterpret_cast<uint4*>(&Vs[d * 64 + ((cb ^ (d & 7)) * 8)]) =
        *reinterpret_cast<const uint4*>(vtb + (size_t)(h * VD + d) * TT + kt0 + cb * 8);
    }
    __syncthreads();

    // S = Q K^T : 16 x 64 per wave
    f32x4 s[4] = {};
    __builtin_amdgcn_s_setprio(1);
#pragma unroll
    for (int kc = 0; kc < 6; ++kc) {
#pragma unroll
      for (int jj = 0; jj < 4; ++jj) {
        int rb = jj * 16 + fr;
        short8 b = *reinterpret_cast<const short8*>(
            &Ks[rb * 192 + (((kc * 4 + fg) ^ (rb & 7)) * 8)]);
        s[jj] = __builtin_amdgcn_mfma_f32_16x16x32_bf16(qf[kc], b, s[jj], 0, 0, 0);
      }
    }
    __builtin_amdgcn_s_setprio(0);

    const bool diag = (kt == qi);
#pragma unroll
    for (int r = 0; r < 4; ++r) {
      float sv[4];
#pragma unroll
      for (int jj = 0; jj < 4; ++jj) {
        float x = s[jj][r] * scale;
        if (diag && (jj * 16 + fr) > (wave * 16 + fg * 4 + r)) x = -1e30f;
        sv[jj] = x;
      }
      float mx = fmaxf(fmaxf(sv[0], sv[1]), fmaxf(sv[2], sv[3]));
#pragma unroll
      for (int off = 1; off < 16; off <<= 1)
        mx = fmaxf(mx, __shfl_xor(mx, off));
      float mn = fmaxf(m[r], mx);
      float corr = __expf(m[r] - mn);
      m[r] = mn;
      float ssum = 0.f;
      float p[4];
#pragma unroll
      for (int jj = 0; jj < 4; ++jj) {
        p[jj] = __expf(sv[jj] - mn);
        ssum += p[jj];
      }
#pragma unroll
      for (int off = 1; off < 16; off <<= 1)
        ssum += __shfl_xor(ssum, off);
      l[r] = l[r] * corr + ssum;
#pragma unroll
      for (int dj = 0; dj < 8; ++dj) o[dj][r] *= corr;
      int prow = fg * 4 + r;
#pragma unroll
      for (int jj = 0; jj < 4; ++jj)
        Ps[wave][prow * 64 + ((jj * 16 + fr) ^ ((prow & 7) << 3))] = f2bf(p[jj]);
    }

    // O += P V
    __builtin_amdgcn_s_setprio(1);
#pragma unroll
    for (int kc = 0; kc < 2; ++kc) {
      short8 p = *reinterpret_cast<const short8*>(
          &Ps[wave][fr * 64 + (((kc * 4 + fg) ^ (fr & 7)) * 8)]);
#pragma unroll
      for (int dj = 0; dj < 8; ++dj) {
        int rv = dj * 16 + fr;
        short8 b = *reinterpret_cast<const short8*>(
            &Vs[rv * 64 + (((kc * 4 + fg) ^ (rv & 7)) * 8)]);
        o[dj] = __builtin_amdgcn_mfma_f32_16x16x32_bf16(p, b, o[dj], 0, 0, 0);
      }
    }
    __builtin_amdgcn_s_setprio(0);
    __syncthreads();
  }

#pragma unroll
  for (int r = 0; r < 4; ++r) {
    float linv = 1.0f / l[r];
    int trow = t0 + wave * 16 + fg * 4 + r;
    unsigned short* orow = out + (size_t)trow * DIM + h * VD;
#pragma unroll
    for (int dj = 0; dj < 8; ++dj)
      orow[dj * 16 + fr] = f2bf(o[dj][r] * linv);
  }
}

// ---------------- launch ----------------
extern "C" void kernel_launch(void* const* d_in, const int* in_sizes, int n_in,
                              void* d_out, int out_size, void* d_ws, size_t ws_size,
                              hipStream_t stream) {
  const float* x        = (const float*)d_in[0];
  const float* w_q_down = (const float*)d_in[1];
  const float* q_norm_w = (const float*)d_in[2];
  const float* w_q_up   = (const float*)d_in[3];
  const float* w_kv_down= (const float*)d_in[4];
  const float* kv_norm_w= (const float*)d_in[5];
  const float* w_kv_up  = (const float*)d_in[6];
  const float* w_o      = (const float*)d_in[7];
  float* outp = (float*)d_out;

  char* ws = (char*)d_ws;
  size_t off = 0;
  auto alloc = [&](size_t bytes) {
    void* p = ws + off;
    off += (bytes + 255) & ~(size_t)255;
    return p;
  };
  float*          kv       = (float*)alloc((size_t)TT * KVD * 4);
  unsigned short* x_bf     = (unsigned short*)alloc((size_t)TT * DIM * 2);   // reused: attn_bf
  unsigned short* wqd_bf   = (unsigned short*)alloc((size_t)Q_RANK * DIM * 2);
  unsigned short* wqu_bf   = (unsigned short*)alloc((size_t)QD * Q_RANK * 2);
  unsigned short* wkvd_bf  = (unsigned short*)alloc((size_t)KVD * DIM * 2);
  unsigned short* wkvu_bf  = (unsigned short*)alloc((size_t)KVUP_D * KV_RANK * 2);
  unsigned short* wo_bf    = (unsigned short*)alloc((size_t)DIM * DIM * 2);
  unsigned short* cqraw_bf = (unsigned short*)alloc((size_t)TT * Q_RANK * 2);
  unsigned short* cq_bf    = (unsigned short*)alloc((size_t)TT * Q_RANK * 2);
  unsigned short* ckv_bf   = (unsigned short*)alloc((size_t)TT * KV_RANK * 2);
  unsigned short* qb_bf    = (unsigned short*)alloc((size_t)TT * QD * 2);
  unsigned short* kvup_bf  = (unsigned short*)alloc((size_t)TT * KVUP_D * 2);
  unsigned short* krope_bf = (unsigned short*)alloc((size_t)TT * ROPE_D * 2);
  unsigned short* vtb      = (unsigned short*)alloc((size_t)NH * VD * TT * 2);
  unsigned short* attn_bf  = x_bf;  // x_bf dead after down-GEMMs

  // batched converts: x + 5 weights (counts are in float4 units)
  {
    int n0 = TT * DIM / 4;
    int n1 = Q_RANK * DIM / 4;
    int n2 = QD * Q_RANK / 4;
    int n3 = KVD * DIM / 4;
    int n4c = KVUP_D * KV_RANK / 4;
    int n5 = DIM * DIM / 4;
    int total = n0 + n1 + n2 + n3 + n4c + n5;
    convert6_kernel<<<dim3((total + 255) / 256), dim3(256), 0, stream>>>(
        x, w_q_down, w_q_up, w_kv_down, w_kv_up, w_o,
        x_bf, wqd_bf, wqu_bf, wkvd_bf, wkvu_bf, wo_bf,
        n0, n1, n2, n3, n4c, n5);
  }

  dim3 blk(256);
  // cq_raw = x @ w_q_down^T   [2048 x 1536], K=2048  (bf16 out)
  gemm_fast<<<dim3(Q_RANK / 128, TT / 128), blk, 0, stream>>>(x_bf, wqd_bf, nullptr, cqraw_bf, DIM, DIM, DIM, Q_RANK);
  // kv = x @ w_kv_down^T      [2048 x 576], K=2048 (fp32, N not /128)
  gemm_bf16_nt<<<dim3(KVD / 64, TT / 64), blk, 0, stream>>>(x_bf, wkvd_bf, kv, DIM, DIM, DIM, KVD);
  rmsnorm_bf16<<<dim3(TT), blk, 0, stream>>>(cqraw_bf, q_norm_w, cq_bf, Q_RANK);
  rmsnorm_f32<<<dim3(TT), blk, 0, stream>>>(kv, kv_norm_w, ckv_bf, KV_RANK, KVD, KV_RANK);
  // q = c_q @ w_q_up^T        [2048 x 3072], K=1536  (bf16 out)
  gemm_fast<<<dim3(QD / 128, TT / 128), blk, 0, stream>>>(cq_bf, wqu_bf, nullptr, qb_bf, Q_RANK, Q_RANK, Q_RANK, QD);
  // kv_up = c_kv @ w_kv_up^T  [2048 x 4096], K=512   (bf16 out)
  gemm_fast<<<dim3(KVUP_D / 128, TT / 128), blk, 0, stream>>>(ckv_bf, wkvu_bf, nullptr, kvup_bf, KV_RANK, KV_RANK, KV_RANK, KVUP_D);
  rope_kernel<<<dim3(TT), blk, 0, stream>>>(qb_bf, kv, krope_bf);
  vtrans_kernel<<<dim3(TT / 64, VD / 64, NH), blk, 0, stream>>>(kvup_bf, vtb);
  attn_mfma_kernel<<<dim3(512), blk, 0, stream>>>(qb_bf, kvup_bf, krope_bf, vtb, attn_bf);
  // out = attn @ w_o^T        [2048 x 2048], K=2048  (fp32 out)
  gemm_fast<<<dim3(DIM / 128, TT / 128), blk, 0, stream>>>(attn_bf, wo_bf, outp, nullptr, DIM, DIM, DIM, DIM);
}

// Round 5
// 245.273 us; speedup vs baseline: 4.7638x; 1.1534x over previous
//
#include <hip/hip_runtime.h>
#include <hip/hip_bf16.h>

typedef short short8 __attribute__((ext_vector_type(8)));
typedef float f32x4 __attribute__((ext_vector_type(4)));

#define DIM 2048
#define NH 16
#define KV_RANK 512
#define Q_RANK 1536
#define ROPE_D 64
#define NOPE 128
#define VD 128
#define TT 2048
#define QKH 192                   // NOPE + ROPE
#define QD (NH * QKH)             // 3072
#define KVUP_D (NH * (NOPE + VD)) // 4096
#define WDN 2176                  // padded combined down-proj N (1536 + 576 + 64 pad)

__device__ inline unsigned short f2bf(float f) {
  __hip_bfloat16 h = __float2bfloat16(f);
  union { __hip_bfloat16 h; unsigned short u; } cv; cv.h = h; return cv.u;
}
__device__ inline float bf2f(unsigned short u) {
  union { unsigned int i; float f; } cv; cv.i = ((unsigned int)u) << 16; return cv.f;
}
__device__ inline void gload_lds16(const void* g, void* l) {
  __builtin_amdgcn_global_load_lds(
      (const __attribute__((address_space(1))) void*)g,
      (__attribute__((address_space(3))) void*)l, 16, 0, 0);
}

// ---------------- all fp32 -> bf16 converts in one launch ----------------
__global__ __launch_bounds__(256) void convert_all(
    const float* __restrict__ x, const float* __restrict__ wqd,
    const float* __restrict__ wkvd, const float* __restrict__ wqu,
    const float* __restrict__ wkvu, const float* __restrict__ wo,
    unsigned short* __restrict__ xb, unsigned short* __restrict__ wdb,
    unsigned short* __restrict__ wqub, unsigned short* __restrict__ wkvub,
    unsigned short* __restrict__ wob) {
  int i = blockIdx.x * 256 + threadIdx.x;
  const int n0 = TT * DIM / 4;
  const int n1 = WDN * 2048 / 4;
  const int n2 = QD * Q_RANK / 4;
  const int n3 = KVUP_D * KV_RANK / 4;
  const int n4 = DIM * DIM / 4;
  float4 v;
  unsigned short* dst;
  if (i < n0) { v = reinterpret_cast<const float4*>(x)[i]; dst = xb; }
  else if ((i -= n0) < n1) {
    int row = i >> 9, c4 = i & 511;   // 512 float4 per 2048-col row
    if (row < 1536)      v = reinterpret_cast<const float4*>(wqd)[row * 512 + c4];
    else if (row < 2112) v = reinterpret_cast<const float4*>(wkvd)[(row - 1536) * 512 + c4];
    else                 v = make_float4(0.f, 0.f, 0.f, 0.f);
    dst = wdb;
  }
  else if ((i -= n1) < n2) { v = reinterpret_cast<const float4*>(wqu)[i]; dst = wqub; }
  else if ((i -= n2) < n3) { v = reinterpret_cast<const float4*>(wkvu)[i]; dst = wkvub; }
  else if ((i -= n3) < n4) { v = reinterpret_cast<const float4*>(wo)[i]; dst = wob; }
  else return;
  ushort4 o;
  o.x = f2bf(v.x); o.y = f2bf(v.y); o.z = f2bf(v.z); o.w = f2bf(v.w);
  reinterpret_cast<ushort4*>(dst)[i] = o;
}

// ------- shared GEMM core: 128x128 tile, BK=64, 2-phase dbuf pipeline -------
// raw s_barrier + counted vmcnt so prefetch loads stay in flight across barriers.
__device__ __forceinline__ void gemm_core(const unsigned short* __restrict__ A,
                                          const unsigned short* __restrict__ W,
                                          unsigned short* As, unsigned short* Bs,
                                          int K, int lda, int ldb,
                                          int bm, int bn, int tid,
                                          f32x4 (&acc)[4][4]) {
  const int lane = tid & 63, wave = tid >> 6;
  const int wm = (wave >> 1) * 64, wn = (wave & 1) * 64;
  const int fr = lane & 15, fg = lane >> 4;
  const int sr = lane >> 3, scb = (lane & 7) ^ sr;  // pre-swizzled source col-block
  const int r0 = wave * 32;

  const unsigned short* Ag = A + (size_t)(bm + r0 + sr) * lda + scb * 8;
  const unsigned short* Wg = W + (size_t)(bn + r0 + sr) * ldb + scb * 8;
  const int nt = K >> 6;

  // prologue: stage tile 0 into buf 0
#pragma unroll
  for (int i = 0; i < 4; ++i) {
    gload_lds16(Ag + (size_t)(i * 8) * lda, As + r0 * 64 + i * 512);
    gload_lds16(Wg + (size_t)(i * 8) * ldb, Bs + r0 * 64 + i * 512);
  }
  int cur = 0;
  for (int t = 0; t < nt; ++t) {
    if (t + 1 < nt) {
      const int nb = cur ^ 1;
      const int ko = (t + 1) * 64;
#pragma unroll
      for (int i = 0; i < 4; ++i) {
        gload_lds16(Ag + ko + (size_t)(i * 8) * lda, As + nb * 8192 + r0 * 64 + i * 512);
        gload_lds16(Wg + ko + (size_t)(i * 8) * ldb, Bs + nb * 8192 + r0 * 64 + i * 512);
      }
      asm volatile("s_waitcnt vmcnt(8)" ::: "memory");  // current buf done, next 8 in flight
    } else {
      asm volatile("s_waitcnt vmcnt(0)" ::: "memory");
    }
    __builtin_amdgcn_s_barrier();
    asm volatile("" ::: "memory");  // keep ds_reads below the barrier
    const unsigned short* Ac = As + cur * 8192;
    const unsigned short* Bc = Bs + cur * 8192;
    __builtin_amdgcn_s_setprio(1);
#pragma unroll
    for (int kk = 0; kk < 2; ++kk) {
      short8 a[4], b[4];
#pragma unroll
      for (int i = 0; i < 4; ++i) {
        int ra = wm + i * 16 + fr;
        a[i] = *reinterpret_cast<const short8*>(&Ac[ra * 64 + (((kk * 4 + fg) ^ (ra & 7)) * 8)]);
        int rb = wn + i * 16 + fr;
        b[i] = *reinterpret_cast<const short8*>(&Bc[rb * 64 + (((kk * 4 + fg) ^ (rb & 7)) * 8)]);
      }
#pragma unroll
      for (int i = 0; i < 4; ++i)
#pragma unroll
        for (int j = 0; j < 4; ++j)
          acc[i][j] = __builtin_amdgcn_mfma_f32_16x16x32_bf16(a[i], b[j], acc[i][j], 0, 0, 0);
    }
    __builtin_amdgcn_s_setprio(0);
    asm volatile("" ::: "memory");  // keep ds_reads above the barrier
    __builtin_amdgcn_s_barrier();
    cur ^= 1;
  }
}

// ------- single GEMM: C = A * W^T, fp32 (Cf) or bf16 (Cb) output -------
__global__ __launch_bounds__(256) void gemm_fast(const unsigned short* __restrict__ A,
                                                 const unsigned short* __restrict__ W,
                                                 float* __restrict__ Cf,
                                                 unsigned short* __restrict__ Cb,
                                                 int K, int lda, int ldb, int ldc) {
  __shared__ __align__(16) unsigned short As[2 * 128 * 64];
  __shared__ __align__(16) unsigned short Bs[2 * 128 * 64];
  const int tid = threadIdx.x;
  const int bm = blockIdx.y * 128, bn = blockIdx.x * 128;
  const int lane = tid & 63, wave = tid >> 6;
  const int wm = (wave >> 1) * 64, wn = (wave & 1) * 64;
  const int fr = lane & 15, fg = lane >> 4;

  f32x4 acc[4][4] = {};
  gemm_core(A, W, As, Bs, K, lda, ldb, bm, bn, tid, acc);

  if (Cb) {
#pragma unroll
    for (int i = 0; i < 4; ++i) {
      int row0 = bm + wm + i * 16 + fg * 4;
#pragma unroll
      for (int j = 0; j < 4; ++j) {
        int col = bn + wn + j * 16 + fr;
#pragma unroll
        for (int r = 0; r < 4; ++r)
          Cb[(size_t)(row0 + r) * ldc + col] = f2bf(acc[i][j][r]);
      }
    }
  } else {
#pragma unroll
    for (int i = 0; i < 4; ++i) {
      int row0 = bm + wm + i * 16 + fg * 4;
#pragma unroll
      for (int j = 0; j < 4; ++j) {
        int col = bn + wn + j * 16 + fr;
#pragma unroll
        for (int r = 0; r < 4; ++r)
          Cf[(size_t)(row0 + r) * ldc + col] = acc[i][j][r];
      }
    }
  }
}

// ------- dual GEMM: blocks 0..383 qup, 384..895 kvup (+V^T side-write) -------
__global__ __launch_bounds__(256) void gemm_dual(
    const unsigned short* __restrict__ A1, const unsigned short* __restrict__ W1,
    unsigned short* __restrict__ C1,
    const unsigned short* __restrict__ A2, const unsigned short* __restrict__ W2,
    unsigned short* __restrict__ C2, unsigned short* __restrict__ vt) {
  __shared__ __align__(16) unsigned short As[2 * 128 * 64];
  __shared__ __align__(16) unsigned short Bs[2 * 128 * 64];
  const int tid = threadIdx.x;
  const int bx = blockIdx.x;
  const unsigned short *A, *W;
  unsigned short* C;
  int K, lda, ldc, bm, bn;
  bool vwrite = false;
  if (bx < 384) {
    A = A1; W = W1; C = C1; K = Q_RANK; lda = Q_RANK; ldc = QD;
    bn = (bx % 24) * 128; bm = (bx / 24) * 128;
  } else {
    int b2 = bx - 384;
    A = A2; W = W2; C = C2; K = KV_RANK; lda = KV_RANK; ldc = KVUP_D;
    bn = (b2 & 31) * 128; bm = (b2 >> 5) * 128;
    vwrite = (bn & 128) != 0;
  }
  const int lane = tid & 63, wave = tid >> 6;
  const int wm = (wave >> 1) * 64, wn = (wave & 1) * 64;
  const int fr = lane & 15, fg = lane >> 4;

  f32x4 acc[4][4] = {};
  gemm_core(A, W, As, Bs, K, lda, lda, bm, bn, tid, acc);

#pragma unroll
  for (int i = 0; i < 4; ++i) {
    int row0 = bm + wm + i * 16 + fg * 4;
#pragma unroll
    for (int j = 0; j < 4; ++j) {
      int col = bn + wn + j * 16 + fr;
#pragma unroll
      for (int r = 0; r < 4; ++r)
        C[(size_t)(row0 + r) * ldc + col] = f2bf(acc[i][j][r]);
    }
  }
  if (vwrite) {
    const int hh = bn >> 8;
#pragma unroll
    for (int i = 0; i < 4; ++i) {
      int t0r = bm + wm + i * 16 + fg * 4;
#pragma unroll
      for (int j = 0; j < 4; ++j) {
        int d = wn + j * 16 + fr;
        ushort4 w4;
        w4.x = f2bf(acc[i][j][0]); w4.y = f2bf(acc[i][j][1]);
        w4.z = f2bf(acc[i][j][2]); w4.w = f2bf(acc[i][j][3]);
        *reinterpret_cast<ushort4*>(vt + (size_t)(hh * VD + d) * TT + t0r) = w4;
      }
    }
  }
}

// ------- RMSNorm rows, bf16 in/out with stride/offset -------
__global__ __launch_bounds__(256) void rmsnorm_bf16(const unsigned short* __restrict__ in,
                                                    int instride, int inoff,
                                                    const float* __restrict__ w,
                                                    unsigned short* __restrict__ out,
                                                    int outstride, int cols) {
  const int row = blockIdx.x, tid = threadIdx.x;
  const unsigned short* x = in + (size_t)row * instride + inoff;
  const int nch = cols >> 3;
  float ss = 0.f;
  for (int cb = tid; cb < nch; cb += 256) {
    short8 v = *reinterpret_cast<const short8*>(x + cb * 8);
#pragma unroll
    for (int e = 0; e < 8; ++e) { float f = bf2f((unsigned short)v[e]); ss += f * f; }
  }
  __shared__ float red[256];
  red[tid] = ss; __syncthreads();
  for (int off = 128; off > 0; off >>= 1) {
    if (tid < off) red[tid] += red[tid + off];
    __syncthreads();
  }
  float r = rsqrtf(red[0] / (float)cols + 1e-6f);
  for (int cb = tid; cb < nch; cb += 256) {
    short8 v = *reinterpret_cast<const short8*>(x + cb * 8);
    ushort4 o0, o1;
    o0.x = f2bf(bf2f((unsigned short)v[0]) * r * w[cb * 8 + 0]);
    o0.y = f2bf(bf2f((unsigned short)v[1]) * r * w[cb * 8 + 1]);
    o0.z = f2bf(bf2f((unsigned short)v[2]) * r * w[cb * 8 + 2]);
    o0.w = f2bf(bf2f((unsigned short)v[3]) * r * w[cb * 8 + 3]);
    o1.x = f2bf(bf2f((unsigned short)v[4]) * r * w[cb * 8 + 4]);
    o1.y = f2bf(bf2f((unsigned short)v[5]) * r * w[cb * 8 + 5]);
    o1.z = f2bf(bf2f((unsigned short)v[6]) * r * w[cb * 8 + 6]);
    o1.w = f2bf(bf2f((unsigned short)v[7]) * r * w[cb * 8 + 7]);
    *reinterpret_cast<ushort4*>(out + (size_t)row * outstride + cb * 8) = o0;
    *reinterpret_cast<ushort4*>(out + (size_t)row * outstride + cb * 8 + 4) = o1;
  }
}

// ------- RoPE in-place on bf16 q rows + k_rope extraction (bf16 src) -------
__global__ __launch_bounds__(256) void rope_kernel(unsigned short* __restrict__ qb,
                                                   const unsigned short* __restrict__ cqkv,
                                                   unsigned short* __restrict__ kr) {
  const int t = blockIdx.x, tid = threadIdx.x;
  unsigned short* qrow = qb + (size_t)t * QD;
  for (int p = tid; p < NH * 32 + 32; p += 256) {
    int j = (p < NH * 32) ? (p & 31) : (p - NH * 32);
    float inv = powf(500000.0f, -(float)(2 * j) * (1.0f / 64.0f));
    float ang = (float)t * inv;
    float sv, cv;
    sincosf(ang, &sv, &cv);
    if (p < NH * 32) {
      int h = p >> 5;
      unsigned short* b = qrow + h * QKH + NOPE + 2 * j;
      float e = bf2f(b[0]), o = bf2f(b[1]);
      b[0] = f2bf(e * cv - o * sv);
      b[1] = f2bf(o * cv + e * sv);
    } else {
      const unsigned short* b = cqkv + (size_t)t * WDN + 2048 + 2 * j;
      float e = bf2f(b[0]), o = bf2f(b[1]);
      kr[(size_t)t * ROPE_D + 2 * j]     = f2bf(e * cv - o * sv);
      kr[(size_t)t * ROPE_D + 2 * j + 1] = f2bf(o * cv + e * sv);
    }
  }
}

// ---------------- k-split MFMA flash attention, partial pass ----------------
// 1280 blocks: (h, qi, chunk). Chunk = 8 k-tiles of 64 keys = 512 keys.
// Writes unnormalized partial O (bf16) + per-row (m, l) for the combine pass.
__global__ __launch_bounds__(256) void attn_part(
    const unsigned short* __restrict__ qb,     // [T][3072] (rope applied)
    const unsigned short* __restrict__ kvupb,  // [T][4096]
    const unsigned short* __restrict__ kropeb, // [T][64]
    const unsigned short* __restrict__ vtb,    // [H*128][T]
    unsigned short* __restrict__ Opart,        // [2048 slots][64][128] bf16
    float* __restrict__ ml)                    // [2048 slots][64][2]
{
  const int b = (int)gridDim.x - 1 - (int)blockIdx.x;  // long chunks first
  const int h = b / 80;
  const int w = b - h * 80;
  int qi, c;
  if (w < 8)       { qi = w;                  c = 0; }
  else if (w < 24) { qi = 8 + ((w - 8) >> 1);  c = (w - 8) & 1; }
  else if (w < 48) { qi = 16 + (w - 24) / 3;   c = (w - 24) % 3; }
  else             { qi = 24 + ((w - 48) >> 2); c = (w - 48) & 3; }
  const int t0 = qi * 64;
  const int ktlo = c * 8;
  const int kthi = min(ktlo + 8, qi + 1);
  const int tid = threadIdx.x;
  const int lane = tid & 63, wave = tid >> 6;
  const int fr = lane & 15, fg = lane >> 4;

  __shared__ __align__(16) unsigned short Ks[64 * 192];
  __shared__ __align__(16) unsigned short Vs[128 * 64];
  __shared__ __align__(16) unsigned short Ps[4][16 * 64];

  short8 qf[6];
  {
    const unsigned short* qrow = qb + (size_t)(t0 + wave * 16 + fr) * QD + h * QKH;
#pragma unroll
    for (int kc = 0; kc < 6; ++kc)
      qf[kc] = *reinterpret_cast<const short8*>(qrow + kc * 32 + fg * 8);
  }

  f32x4 o[8] = {};
  float m[4] = {-1e30f, -1e30f, -1e30f, -1e30f};
  float l[4] = {0.f, 0.f, 0.f, 0.f};
  const float scale = 0.0721687836487032f;  // 1/sqrt(192)

  for (int kt = ktlo; kt < kthi; ++kt) {
    const int kt0 = kt * 64;
    // stage K: linear LDS dest, inverse-swizzled global source (rule 21)
#pragma unroll
    for (int i = 0; i < 6; ++i) {
      int u = tid + i * 256;
      int row = u / 24, cb = u - (u / 24) * 24;
      int cbs = cb ^ (row & 7);
      const unsigned short* src = (cb < 16)
        ? kvupb + (size_t)(kt0 + row) * KVUP_D + h * 256 + cbs * 8
        : kropeb + (size_t)(kt0 + row) * ROPE_D + (cbs - 16) * 8;
      gload_lds16(src, Ks + u * 8);
    }
    // stage V^T
#pragma unroll
    for (int i = 0; i < 4; ++i) {
      int u = tid + i * 256;
      int d = u >> 3, cb = u & 7;
      int cbs = cb ^ (d & 7);
      gload_lds16(vtb + (size_t)(h * VD + d) * TT + kt0 + cbs * 8, Vs + u * 8);
    }
    __syncthreads();

    f32x4 s[4] = {};
    __builtin_amdgcn_s_setprio(1);
#pragma unroll
    for (int kc = 0; kc < 6; ++kc) {
#pragma unroll
      for (int jj = 0; jj < 4; ++jj) {
        int rb = jj * 16 + fr;
        short8 bb = *reinterpret_cast<const short8*>(
            &Ks[rb * 192 + (((kc * 4 + fg) ^ (rb & 7)) * 8)]);
        s[jj] = __builtin_amdgcn_mfma_f32_16x16x32_bf16(qf[kc], bb, s[jj], 0, 0, 0);
      }
    }
    __builtin_amdgcn_s_setprio(0);

    const bool diag = (kt == qi);
#pragma unroll
    for (int r = 0; r < 4; ++r) {
      float sv[4];
#pragma unroll
      for (int jj = 0; jj < 4; ++jj) {
        float xx = s[jj][r] * scale;
        if (diag && (jj * 16 + fr) > (wave * 16 + fg * 4 + r)) xx = -1e30f;
        sv[jj] = xx;
      }
      float mx = fmaxf(fmaxf(sv[0], sv[1]), fmaxf(sv[2], sv[3]));
#pragma unroll
      for (int off = 1; off < 16; off <<= 1)
        mx = fmaxf(mx, __shfl_xor(mx, off));
      if (mx > m[r]) {  // exact defer: rescale only when max grows
        float corr = __expf(m[r] - mx);
        m[r] = mx;
        l[r] *= corr;
#pragma unroll
        for (int dj = 0; dj < 8; ++dj) o[dj][r] *= corr;
      }
      float ssum = 0.f;
      float p[4];
#pragma unroll
      for (int jj = 0; jj < 4; ++jj) {
        p[jj] = __expf(sv[jj] - m[r]);
        ssum += p[jj];
      }
#pragma unroll
      for (int off = 1; off < 16; off <<= 1)
        ssum += __shfl_xor(ssum, off);
      l[r] += ssum;
      int prow = fg * 4 + r;
#pragma unroll
      for (int jj = 0; jj < 4; ++jj)
        Ps[wave][prow * 64 + ((jj * 16 + fr) ^ ((prow & 7) << 3))] = f2bf(p[jj]);
    }

    __builtin_amdgcn_s_setprio(1);
#pragma unroll
    for (int kc = 0; kc < 2; ++kc) {
      short8 p = *reinterpret_cast<const short8*>(
          &Ps[wave][fr * 64 + (((kc * 4 + fg) ^ (fr & 7)) * 8)]);
#pragma unroll
      for (int dj = 0; dj < 8; ++dj) {
        int rv = dj * 16 + fr;
        short8 bb = *reinterpret_cast<const short8*>(
            &Vs[rv * 64 + (((kc * 4 + fg) ^ (rv & 7)) * 8)]);
        o[dj] = __builtin_amdgcn_mfma_f32_16x16x32_bf16(p, bb, o[dj], 0, 0, 0);
      }
    }
    __builtin_amdgcn_s_setprio(0);
    __syncthreads();
  }

  const int slot = (h * 32 + qi) * 4 + c;
#pragma unroll
  for (int r = 0; r < 4; ++r) {
    int row = wave * 16 + fg * 4 + r;
    unsigned short* orow = Opart + ((size_t)slot * 64 + row) * 128;
#pragma unroll
    for (int dj = 0; dj < 8; ++dj)
      orow[dj * 16 + fr] = f2bf(o[dj][r]);
    if (fr == 0) {
      ml[((size_t)slot * 64 + row) * 2]     = m[r];
      ml[((size_t)slot * 64 + row) * 2 + 1] = l[r];
    }
  }
}

// ---------------- combine partials -> attn output (bf16) ----------------
__global__ __launch_bounds__(256) void attn_combine(
    const unsigned short* __restrict__ Opart, const float* __restrict__ ml,
    unsigned short* __restrict__ out) {
  const int bid = blockIdx.x;          // h*32 + qi
  const int h = bid >> 5, qi = bid & 31;
  const int nch = (qi >> 3) + 1;
  const int tid = threadIdx.x;
  const int row = tid >> 2, dg = tid & 3;
  const int base = bid * 4;
  float mm[4], ll[4];
  float M = -1e30f;
#pragma unroll
  for (int cc = 0; cc < 4; ++cc) {
    if (cc < nch) {
      mm[cc] = ml[((size_t)(base + cc) * 64 + row) * 2];
      ll[cc] = ml[((size_t)(base + cc) * 64 + row) * 2 + 1];
      M = fmaxf(M, mm[cc]);
    } else { mm[cc] = -1e30f; ll[cc] = 0.f; }
  }
  float L = 0.f;
#pragma unroll
  for (int cc = 0; cc < 4; ++cc) {
    mm[cc] = __expf(mm[cc] - M);
    L += ll[cc] * mm[cc];
  }
  float acc[32] = {};
#pragma unroll
  for (int cc = 0; cc < 4; ++cc) {
    if (cc < nch) {
      const unsigned short* op = Opart + ((size_t)(base + cc) * 64 + row) * 128 + dg * 32;
      float sc = mm[cc];
#pragma unroll
      for (int e8 = 0; e8 < 4; ++e8) {
        short8 v = *reinterpret_cast<const short8*>(op + e8 * 8);
#pragma unroll
        for (int e = 0; e < 8; ++e) acc[e8 * 8 + e] += bf2f((unsigned short)v[e]) * sc;
      }
    }
  }
  float linv = 1.0f / L;
  unsigned short* dst = out + (size_t)(qi * 64 + row) * DIM + h * VD + dg * 32;
#pragma unroll
  for (int e4 = 0; e4 < 8; ++e4) {
    ushort4 w4;
    w4.x = f2bf(acc[e4 * 4 + 0] * linv);
    w4.y = f2bf(acc[e4 * 4 + 1] * linv);
    w4.z = f2bf(acc[e4 * 4 + 2] * linv);
    w4.w = f2bf(acc[e4 * 4 + 3] * linv);
    *reinterpret_cast<ushort4*>(dst + e4 * 4) = w4;
  }
}

// ---------------- launch ----------------
extern "C" void kernel_launch(void* const* d_in, const int* in_sizes, int n_in,
                              void* d_out, int out_size, void* d_ws, size_t ws_size,
                              hipStream_t stream) {
  const float* x        = (const float*)d_in[0];
  const float* w_q_down = (const float*)d_in[1];
  const float* q_norm_w = (const float*)d_in[2];
  const float* w_q_up   = (const float*)d_in[3];
  const float* w_kv_down= (const float*)d_in[4];
  const float* kv_norm_w= (const float*)d_in[5];
  const float* w_kv_up  = (const float*)d_in[6];
  const float* w_o      = (const float*)d_in[7];
  float* outp = (float*)d_out;

  char* ws = (char*)d_ws;
  size_t off = 0;
  auto alloc = [&](size_t bytes) {
    void* p = ws + off;
    off += (bytes + 255) & ~(size_t)255;
    return p;
  };
  unsigned short* x_bf     = (unsigned short*)alloc((size_t)TT * DIM * 2);   // reused: attn_bf
  unsigned short* wdown_bf = (unsigned short*)alloc((size_t)WDN * DIM * 2);
  unsigned short* wqu_bf   = (unsigned short*)alloc((size_t)QD * Q_RANK * 2);
  unsigned short* wkvu_bf  = (unsigned short*)alloc((size_t)KVUP_D * KV_RANK * 2);
  unsigned short* wo_bf    = (unsigned short*)alloc((size_t)DIM * DIM * 2);
  unsigned short* cqkv_bf  = (unsigned short*)alloc((size_t)TT * WDN * 2);
  unsigned short* cq_bf    = (unsigned short*)alloc((size_t)TT * Q_RANK * 2);
  unsigned short* ckv_bf   = (unsigned short*)alloc((size_t)TT * KV_RANK * 2);
  unsigned short* qb_bf    = (unsigned short*)alloc((size_t)TT * QD * 2);
  unsigned short* kvup_bf  = (unsigned short*)alloc((size_t)TT * KVUP_D * 2);
  unsigned short* krope_bf = (unsigned short*)alloc((size_t)TT * ROPE_D * 2);
  unsigned short* vtb      = (unsigned short*)alloc((size_t)NH * VD * TT * 2);
  unsigned short* Opart    = (unsigned short*)alloc((size_t)2048 * 64 * 128 * 2);
  float*          mlbuf    = (float*)alloc((size_t)2048 * 64 * 2 * 4);
  unsigned short* attn_bf  = x_bf;  // x_bf dead after down-GEMM

  {
    int total = TT * DIM / 4 + WDN * 2048 / 4 + QD * Q_RANK / 4 +
                KVUP_D * KV_RANK / 4 + DIM * DIM / 4;
    convert_all<<<dim3((total + 255) / 256), dim3(256), 0, stream>>>(
        x, w_q_down, w_kv_down, w_q_up, w_kv_up, w_o,
        x_bf, wdown_bf, wqu_bf, wkvu_bf, wo_bf);
  }

  dim3 blk(256);
  // combined down-proj: cqkv = x @ [w_q_down; w_kv_down; pad]^T  [2048 x 2176]
  gemm_fast<<<dim3(WDN / 128, TT / 128), blk, 0, stream>>>(
      x_bf, wdown_bf, nullptr, cqkv_bf, DIM, DIM, DIM, WDN);
  rmsnorm_bf16<<<dim3(TT), blk, 0, stream>>>(cqkv_bf, WDN, 0, q_norm_w, cq_bf, Q_RANK, Q_RANK);
  rmsnorm_bf16<<<dim3(TT), blk, 0, stream>>>(cqkv_bf, WDN, Q_RANK, kv_norm_w, ckv_bf, KV_RANK, KV_RANK);
  // qup + kvup in one dispatch (kvup side also writes V^T)
  gemm_dual<<<dim3(896), blk, 0, stream>>>(cq_bf, wqu_bf, qb_bf,
                                           ckv_bf, wkvu_bf, kvup_bf, vtb);
  rope_kernel<<<dim3(TT), blk, 0, stream>>>(qb_bf, cqkv_bf, krope_bf);
  attn_part<<<dim3(1280), blk, 0, stream>>>(qb_bf, kvup_bf, krope_bf, vtb, Opart, mlbuf);
  attn_combine<<<dim3(512), blk, 0, stream>>>(Opart, mlbuf, attn_bf);
  // out = attn @ w_o^T  [2048 x 2048]
  gemm_fast<<<dim3(DIM / 128, TT / 128), blk, 0, stream>>>(
      attn_bf, wo_bf, outp, nullptr, DIM, DIM, DIM, DIM);
}